// Round 9
// baseline (212.758 us; speedup 1.0000x reference)
//
#include <hip/hip_runtime.h>
#include <hip/hip_fp16.h>
#include <math.h>

#define D_MODEL 1024
#define NH 16
#define HD 64
#define SEQ 2048
#define BATCH 2
#define MROWS (BATCH*SEQ)   // 4096
#define KDIM 1024

typedef unsigned short u16;
typedef __attribute__((ext_vector_type(8))) _Float16 h8;   // 8 f16 (4 VGPRs)
typedef __attribute__((ext_vector_type(8))) short s8v;
typedef __attribute__((ext_vector_type(4))) float f4v;

#define MFMAH(a, b, c) __builtin_amdgcn_mfma_f32_16x16x32_f16(a, b, c, 0, 0, 0)

// async global->LDS DMA, 16B/lane; LDS dest must be wave-uniform base
__device__ __forceinline__ void gld16(const u16* g, u16* l) {
    __builtin_amdgcn_global_load_lds(
        (const __attribute__((address_space(1))) void*)g,
        (__attribute__((address_space(3))) void*)l, 16, 0, 0);
}

__device__ __forceinline__ u16 f32_to_f16(float f) {
    return __half_as_ushort(__float2half(f));   // v_cvt_f16_f32, RNE
}

// ---------------------------------------------------------------------------
// fp32 -> fp16 conversion for x (4M) + 4 W (1M each), 8 elems/thread, PLUS
// RoPE cos/sin table build (blocks 4096..4351): ropeT[s*32+dd].
// ---------------------------------------------------------------------------
__global__ __launch_bounds__(256)
void convert_f16(const float* __restrict__ x,
                 const float* __restrict__ Wq, const float* __restrict__ Wk,
                 const float* __restrict__ Wv, const float* __restrict__ Wo,
                 u16* __restrict__ xF,
                 u16* __restrict__ WqF, u16* __restrict__ WkF,
                 u16* __restrict__ WvF, u16* __restrict__ WoF,
                 float2* __restrict__ ropeT) {
    int i = blockIdx.x * 256 + threadIdx.x;
    if (i >= (1 << 20)) {
        // ---- RoPE table: s in [0,2048), dd in [0,32) ----
        int idx2 = i - (1 << 20);          // 0..65535
        int s  = idx2 >> 5;
        int dd = idx2 & 31;
        float inv = __expf(-(float)dd * 0.2878231366f);   // 1e4^(-dd/32)
        float ang = (float)s * inv;
        ropeT[idx2] = make_float2(cosf(ang), sinf(ang));  // same math as before
        return;
    }
    const float* src;
    u16* dst;
    int idx;
    if (i < (1 << 19)) {
        src = x; dst = xF; idx = i;
    } else {
        int j = i - (1 << 19);
        int w = j >> 17;
        idx = j & ((1 << 17) - 1);
        switch (w) {
            case 0:  src = Wq; dst = WqF; break;
            case 1:  src = Wk; dst = WkF; break;
            case 2:  src = Wv; dst = WvF; break;
            default: src = Wo; dst = WoF; break;
        }
    }
    float4 a = ((const float4*)src)[idx * 2];
    float4 b = ((const float4*)src)[idx * 2 + 1];
    s8v o;
    o[0] = (short)f32_to_f16(a.x); o[1] = (short)f32_to_f16(a.y);
    o[2] = (short)f32_to_f16(a.z); o[3] = (short)f32_to_f16(a.w);
    o[4] = (short)f32_to_f16(b.x); o[5] = (short)f32_to_f16(b.y);
    o[6] = (short)f32_to_f16(b.z); o[7] = (short)f32_to_f16(b.w);
    ((s8v*)dst)[idx] = o;
}

// ---------------------------------------------------------------------------
// Fused QKV fp16 MFMA GEMM — BM=128 BN=128 BK=64, 64KB LDS dbuf,
// 2 blocks/CU. global_load_lds w=16, source-side XOR swizzle. Grid 768.
// Q,K: fused RoPE (table) -> LDS-staged full-line stores. K: atomicMax
// row-norm^2. V: LDS transpose -> fp16 [B,H,D,S].  (unchanged from R8)
// ---------------------------------------------------------------------------
__global__ __launch_bounds__(256, 2)
void qkv_gemm(const u16* __restrict__ xF, const u16* __restrict__ WqF,
              const u16* __restrict__ WkF, const u16* __restrict__ WvF,
              const float* __restrict__ bq, const float* __restrict__ bk,
              const float* __restrict__ bv,
              const float2* __restrict__ ropeT,
              u16* __restrict__ QF, u16* __restrict__ KF,
              u16* __restrict__ VtF, float* __restrict__ km2) {
    __shared__ __align__(16) u16 SMEM[32768];   // 64 KB

    const int t    = threadIdx.x;
    const int w    = t >> 6;
    const int lane = t & 63;
    const int quad = lane >> 4;
    const int l15  = lane & 15;
    const int wr   = w >> 1;
    const int wc   = w & 1;

    const int bid  = blockIdx.x;
    const int xcd  = bid & 7;
    const int j    = bid >> 3;          // 0..95
    const int m0   = (xcd * 4 + (j & 3)) * 128;
    const int yt   = j >> 2;            // 0..23
    const int wsel = yt >> 3;
    const int n0   = (yt & 7) * 128;

    const u16* Bg;
    const float* bias;
    if (wsel == 0)      { Bg = WqF; bias = bq; }
    else if (wsel == 1) { Bg = WkF; bias = bk; }
    else                { Bg = WvF; bias = bv; }

    const int lr = lane >> 3;                 // row within seg
    const int lc = (((lane & 7) ^ lr)) * 8;   // swizzled global u16 col

    f4v acc[4][4];
    #pragma unroll
    for (int i = 0; i < 4; i++)
        #pragma unroll
        for (int jj = 0; jj < 4; jj++)
            acc[i][jj] = (f4v){0.f, 0.f, 0.f, 0.f};

#define STAGE(K0, DB) do {                                                   \
    u16* As_ = SMEM + (DB);                                                  \
    u16* Bs_ = As_ + 8192;                                                   \
    _Pragma("unroll")                                                        \
    for (int jj_ = 0; jj_ < 4; jj_++) {                                      \
        int seg = jj_ * 4 + w;                                               \
        gld16(xF + (size_t)(m0 + seg * 8 + lr) * KDIM + (K0) + lc,           \
              As_ + seg * 512);                                              \
        gld16(Bg + (size_t)(n0 + seg * 8 + lr) * KDIM + (K0) + lc,           \
              Bs_ + seg * 512);                                              \
    }                                                                        \
} while (0)

    STAGE(0, 0);
    __syncthreads();

    int buf = 0;
    for (int k0 = 0; k0 < KDIM; k0 += 64) {
        if (k0 + 64 < KDIM) STAGE(k0 + 64, (buf ^ 1) * 16384);

        const u16* As = SMEM + buf * 16384;
        const u16* Bs = As + 8192;
        #pragma unroll
        for (int kk = 0; kk < 2; kk++) {
            const int swz = ((kk * 4 + quad) ^ (l15 & 7)) << 3;
            h8 a[4], b[4];
            #pragma unroll
            for (int mt = 0; mt < 4; mt++)
                a[mt] = *(const h8*)&As[(wr * 64 + mt * 16 + l15) * 64 + swz];
            #pragma unroll
            for (int nt = 0; nt < 4; nt++)
                b[nt] = *(const h8*)&Bs[(wc * 64 + nt * 16 + l15) * 64 + swz];
            #pragma unroll
            for (int mt = 0; mt < 4; mt++)
                #pragma unroll
                for (int nt = 0; nt < 4; nt++)
                    acc[mt][nt] = MFMAH(a[mt], b[nt], acc[mt][nt]);
        }
        __syncthreads();
        buf ^= 1;
    }
#undef STAGE

    const int bb = m0 >> 11;
    const int s0 = m0 & 2047;
    const int h0 = n0 >> 6;             // first of 2 heads in this n-tile

    if (wsel < 2) {
        // ---- Q/K: fused RoPE (table) -> LDS tile [128 s][128 n] swizzled ----
        u16* OF = (wsel == 0) ? QF : KF;
        float kn_max = 0.f;
        #pragma unroll
        for (int mt = 0; mt < 4; mt++) {
            #pragma unroll
            for (int r = 0; r < 4; r++) {
                int R = wr * 64 + mt * 16 + quad * 4 + r;     // local s
                int s = s0 + R;
                float rowsum = 0.f;
                #pragma unroll
                for (int nt = 0; nt < 2; nt++) {
                    int col = wc * 64 + nt * 16 + l15;        // local n
                    int n1 = n0 + col;
                    int dd = n1 & 31;
                    float v1 = acc[mt][nt][r]     + bias[n1];
                    float v2 = acc[mt][nt + 2][r] + bias[n1 + 32];
                    float2 cssn = ropeT[(s << 5) | dd];       // coalesced
                    float cs  = cssn.x;
                    float sn  = cssn.y;
                    float r1 = v1 * cs - v2 * sn;
                    float r2 = v2 * cs + v1 * sn;
                    rowsum += v1 * v1 + v2 * v2;     // norm is RoPE-invariant
                    SMEM[R * 128 + (((col >> 3) ^ (R & 15)) << 3) + (col & 7)]
                        = f32_to_f16(r1);
                    int col2 = col + 32;
                    SMEM[R * 128 + (((col2 >> 3) ^ (R & 15)) << 3) + (col2 & 7)]
                        = f32_to_f16(r2);
                }
                if (wsel == 1) {
                    rowsum += __shfl_xor(rowsum, 1, 64);
                    rowsum += __shfl_xor(rowsum, 2, 64);
                    rowsum += __shfl_xor(rowsum, 4, 64);
                    rowsum += __shfl_xor(rowsum, 8, 64);
                    kn_max = fmaxf(kn_max, rowsum);
                }
            }
        }
        if (wsel == 1) {
            kn_max = fmaxf(kn_max, __shfl_xor(kn_max, 16, 64));
            kn_max = fmaxf(kn_max, __shfl_xor(kn_max, 32, 64));
            if (lane == 0) atomicMax((int*)km2, __float_as_int(kn_max));
        }
        __syncthreads();
        // drain: per instruction each wave writes 1 KB contiguous [B,H,S,D]
        #pragma unroll
        for (int cc = 0; cc < 8; cc++) {
            int idx  = cc * 256 + t;       // 0..2047
            int hl   = idx >> 10;          // 0..1
            int rem  = idx & 1023;
            int R    = rem >> 3;           // local s 0..127
            int dch  = rem & 7;            // 16B chunk along d
            s8v val = *(const s8v*)&SMEM[R * 128 +
                          (((hl * 8 + dch) ^ (R & 15)) << 3)];
            *(s8v*)(OF + (((size_t)bb * NH + h0 + hl) * SEQ + s0 + R) * 64
                       + dch * 8) = val;
        }
    } else {
        // ---- V: transpose via LDS [128 n][128 m], fp16 [B,H,D,S] ----
        #pragma unroll
        for (int mt = 0; mt < 4; mt++) {
            #pragma unroll
            for (int nt = 0; nt < 4; nt++) {
                int n = wc * 64 + nt * 16 + l15;
                float bv_ = bias[n0 + n];
                #pragma unroll
                for (int r = 0; r < 4; r++) {
                    int m = wr * 64 + mt * 16 + quad * 4 + r;
                    float v = acc[mt][nt][r] + bv_;
                    SMEM[n * 128 + (((m >> 3) ^ (n & 15)) << 3) + (m & 7)]
                        = f32_to_f16(v);
                }
            }
        }
        __syncthreads();
        // drain: per instruction a wave covers 4 full d-rows (4 x 256B)
        #pragma unroll
        for (int cc = 0; cc < 8; cc++) {
            int idx = cc * 256 + t;        // 0..2047
            int n   = idx >> 4;            // local col: h*64+d, 0..127
            int mc  = idx & 15;            // 16B chunk along s
            int d   = n & 63;
            int hh  = n >> 6;
            size_t obase = ((size_t)((bb * NH + h0 + hh) * HD + d)) * SEQ + s0;
            s8v val = *(const s8v*)&SMEM[n * 128 + ((mc ^ (n & 15)) << 3)];
            *(s8v*)(VtF + obase + mc * 8) = val;
        }
    }
}

// ---------------------------------------------------------------------------
// MFMA flash attention, Q-tile 64, grid 1024 (4 blocks/CU). Round-9:
// KVBLK 64->128 (16 barrier-iters instead of 32; 4 sub-tiles per stage;
// LDS 38.9KB, still 4 blocks/CU) and exp2-folded softmax (log2e pre-folded
// into scale+bound: kills 8 v_mul per sub-tile).
// Swapped QK^T with key-permuted staging; P in registers (R8-verified).
// ---------------------------------------------------------------------------
__global__ __launch_bounds__(256, 4)
void flash_attn(const u16* __restrict__ QF, const u16* __restrict__ KF,
                const u16* __restrict__ VtF,
                const float* __restrict__ kmax2,
                u16* __restrict__ AOF) {
    __shared__ __align__(16) u16 KS[4][32 * 72];
    __shared__ __align__(16) u16 VtS[4][64 * 40];

    const int t    = threadIdx.x;
    const int w    = t >> 6;
    const int lane = t & 63;
    const int quad = lane >> 4;
    const int l15  = lane & 15;

    const int bid = blockIdx.x;
    const int xcd = bid & 7;
    const int j   = bid >> 3;          // 0..127
    const int bh  = xcd * 4 + (j & 3); // 0..31
    const int q0  = (j >> 2) * 64;     // 0..31 * 64

    const size_t kvbase = (size_t)bh * SEQ * HD;
    const float km2 = kmax2[0];
    const float C1 = 0.125f * 1.44269504089f;   // scale * log2(e)

    // ---- Q fragments; static softmax bound (log2-domain) for q-row l15 ----
    h8 qf[2];
    float mb2;
    {
        const u16* qp = QF + kvbase +
            (size_t)(q0 + w * 16 + l15) * HD + quad * 8;
        qf[0] = *(const h8*)qp;
        qf[1] = *(const h8*)(qp + 32);
        float qn2 = 0.f;
        #pragma unroll
        for (int st = 0; st < 2; st++)
            #pragma unroll
            for (int e = 0; e < 8; e++) {
                float v = (float)qf[st][e];
                qn2 += v * v;
            }
        qn2 += __shfl_xor(qn2, 16, 64);
        qn2 += __shfl_xor(qn2, 32, 64);   // row norm^2, replicated over quads
        mb2 = sqrtf(qn2 * km2) * C1;      // bound already in log2 domain
    }

    f4v o[4];
    #pragma unroll
    for (int nt = 0; nt < 4; nt++) o[nt] = (f4v){0.f, 0.f, 0.f, 0.f};
    float lsum = 0.f;

    // ---- staging addresses; K rows permuted: phys row krow holds key pkey ----
    const int krow = t >> 3;                 // physical LDS row 0..31
    const int kdc  = (t & 7) * 8;            // 16B chunk along d
    const int pkey = (krow & 3) + 8 * ((krow >> 2) & 3) + 4 * (krow >> 4);
    const u16* kgp = KF + kvbase + (size_t)pkey * HD + kdc;
    const int vd   = t >> 2;                 // 0..63
    const int vkc  = (t & 3) * 8;            // 16B chunk along keys
    const int vcol = vkc ^ (((vd >> 3) & 3) << 3);
    const u16* vgp = VtF + (size_t)bh * HD * SEQ + (size_t)vd * SEQ + vkc;

    // prologue: prefetch tile 0 (4 K subtiles + 4 V subtiles) into registers
    s8v krg[4], vrg[4];
    #pragma unroll
    for (int s = 0; s < 4; s++) {
        krg[s] = *(const s8v*)(kgp + (size_t)(32 * s) * HD);
        vrg[s] = *(const s8v*)(vgp + 32 * s);
    }

    for (int k0 = 0; k0 < SEQ; k0 += 128) {
        __syncthreads();                     // prev compute's LDS reads done
        #pragma unroll
        for (int s = 0; s < 4; s++) {
            *(s8v*)&KS[s][krow * 72 + kdc] = krg[s];
            *(s8v*)&VtS[s][vd * 40 + vcol] = vrg[s];
        }
        if (k0 + 128 < SEQ) {
            #pragma unroll
            for (int s = 0; s < 4; s++) {
                krg[s] = *(const s8v*)(kgp +
                             (size_t)(k0 + 128 + 32 * s) * HD);
                vrg[s] = *(const s8v*)(vgp + k0 + 128 + 32 * s);
            }
        }
        __syncthreads();

        #pragma unroll
        for (int sub = 0; sub < 4; sub++) {
            // phys rows l15 / 16+l15 = key groups {a+8b} / {a+8b+4}
            const u16* kb0 = KS[sub] + l15 * 72 + quad * 8;
            const u16* kb1 = KS[sub] + (16 + l15) * 72 + quad * 8;
            h8 kh0 = *(const h8*)kb0, kh1 = *(const h8*)(kb0 + 32);
            h8 kh2 = *(const h8*)kb1, kh3 = *(const h8*)(kb1 + 32);

            // S^T = K·Q^T: lane(l15,quad) reg r = S[q=l15][key 8*quad+r (+4)]
            f4v sc0 = (f4v){0.f, 0.f, 0.f, 0.f};
            f4v sc1 = (f4v){0.f, 0.f, 0.f, 0.f};
            __builtin_amdgcn_s_setprio(1);
            sc0 = MFMAH(kh0, qf[0], sc0);
            sc0 = MFMAH(kh1, qf[1], sc0);
            sc1 = MFMAH(kh2, qf[0], sc1);
            sc1 = MFMAH(kh3, qf[1], sc1);
            __builtin_amdgcn_s_setprio(0);

            // in-register softmax (log2 domain): 8 P values, keys 8q..8q+7
            float p[8];
            #pragma unroll
            for (int r = 0; r < 4; r++) {
                p[r]     = exp2f(sc0[r] * C1 - mb2);
                p[4 + r] = exp2f(sc1[r] * C1 - mb2);
            }
            lsum += ((p[0] + p[1]) + (p[2] + p[3]))
                  + ((p[4] + p[5]) + (p[6] + p[7]));

            // pack to PV B-fragment: slots 0..7 = keys 8q..8q+7
            h8 pb;
            __half2* pp = (__half2*)&pb;
            pp[0] = __floats2half2_rn(p[0], p[1]);
            pp[1] = __floats2half2_rn(p[2], p[3]);
            pp[2] = __floats2half2_rn(p[4], p[5]);
            pp[3] = __floats2half2_rn(p[6], p[7]);

            // O^T += V^T·P^T (V read identical: A/B layout equivalence)
            __builtin_amdgcn_s_setprio(1);
            #pragma unroll
            for (int nt = 0; nt < 4; nt++) {
                int dim = nt * 16 + l15;
                int voff = dim * 40 + ((quad * 8) ^ (((dim >> 3) & 3) << 3));
                o[nt] = MFMAH(*(const h8*)&VtS[sub][voff], pb, o[nt]);
            }
            __builtin_amdgcn_s_setprio(0);
        }
    }

    // ---- epilogue: reduce l over quads, normalize, LDS transpose, store ----
    lsum += __shfl_xor(lsum, 16, 64);
    lsum += __shfl_xor(lsum, 32, 64);
    float inv_l = 1.0f / lsum;

    const int b = bh >> 4;
    const int h = bh & 15;
    u16* OS = &KS[0][0];                 // 8 KB, aliases dead K tiles
    __syncthreads();                     // all waves done reading KS
    const int srow = w * 16 + l15;       // local s 0..63
    #pragma unroll
    for (int nt = 0; nt < 4; nt++) {
        #pragma unroll
        for (int r = 0; r < 4; r++) {
            int d = nt * 16 + quad * 4 + r;
            OS[srow * 64 + (((d >> 3) ^ (srow & 7)) << 3) + (d & 7)]
                = f32_to_f16(o[nt][r] * inv_l);
        }
    }
    __syncthreads();
    // per instruction: wave covers 8 full 128B lines of [B,S,H,D]
    #pragma unroll
    for (int cc = 0; cc < 2; cc++) {
        int idx = cc * 256 + t;          // 0..511
        int sr  = idx >> 3;              // 0..63
        int dch = idx & 7;
        s8v val = *(const s8v*)&OS[sr * 64 + ((dch ^ (sr & 7)) << 3)];
        *(s8v*)(AOF + (((size_t)b * SEQ + q0 + sr) * NH + h) * HD + dch * 8)
            = val;
    }
}

// ---------------------------------------------------------------------------
// Out-projection fp16 MFMA GEMM — BM=128 BN=64 BK=64, grid 512 (unchanged).
// ---------------------------------------------------------------------------
__global__ __launch_bounds__(256, 2)
void gemm_out(const u16* __restrict__ AF, const u16* __restrict__ BF,
              const float* __restrict__ bias, float* __restrict__ out) {
    __shared__ __align__(16) u16 SMEM[24576];   // 48 KB

    const int t    = threadIdx.x;
    const int w    = t >> 6;
    const int lane = t & 63;
    const int quad = lane >> 4;
    const int l15  = lane & 15;
    const int wr   = w >> 1;        // m-half (64 rows)
    const int wc   = w & 1;         // n-half (32 cols)

    const int bid = blockIdx.x;
    const int xcd = bid & 7;
    const int j   = bid >> 3;              // 0..63
    const int m0  = (xcd * 4 + (j & 3)) * 128;
    const int n0  = (j >> 2) * 64;         // 0..15 * 64

    const int lr = lane >> 3;
    const int lc = (((lane & 7) ^ lr)) * 8;

    f4v acc[4][2];
    #pragma unroll
    for (int i = 0; i < 4; i++)
        #pragma unroll
        for (int jj = 0; jj < 2; jj++)
            acc[i][jj] = (f4v){0.f, 0.f, 0.f, 0.f};

#define STAGE(K0, DB) do {                                                   \
    u16* As_ = SMEM + (DB);                                                  \
    u16* Bs_ = As_ + 8192;                                                   \
    _Pragma("unroll")                                                        \
    for (int jj_ = 0; jj_ < 4; jj_++) {                                      \
        int seg = jj_ * 4 + w;                                               \
        gld16(AF + (size_t)(m0 + seg * 8 + lr) * KDIM + (K0) + lc,           \
              As_ + seg * 512);                                              \
    }                                                                        \
    _Pragma("unroll")                                                        \
    for (int jj_ = 0; jj_ < 2; jj_++) {                                      \
        int seg = jj_ * 4 + w;                                               \
        gld16(BF + (size_t)(n0 + seg * 8 + lr) * KDIM + (K0) + lc,           \
              Bs_ + seg * 512);                                              \
    }                                                                        \
} while (0)

    STAGE(0, 0);
    __syncthreads();

    int buf = 0;
    for (int k0 = 0; k0 < KDIM; k0 += 64) {
        if (k0 + 64 < KDIM) STAGE(k0 + 64, (buf ^ 1) * 12288);

        const u16* As = SMEM + buf * 12288;
        const u16* Bs = As + 8192;
        #pragma unroll
        for (int kk = 0; kk < 2; kk++) {
            const int swz = ((kk * 4 + quad) ^ (l15 & 7)) << 3;
            h8 a[4], b[2];
            #pragma unroll
            for (int mt = 0; mt < 4; mt++)
                a[mt] = *(const h8*)&As[(wr * 64 + mt * 16 + l15) * 64 + swz];
            #pragma unroll
            for (int nt = 0; nt < 2; nt++)
                b[nt] = *(const h8*)&Bs[(wc * 32 + nt * 16 + l15) * 64 + swz];
            #pragma unroll
            for (int mt = 0; mt < 4; mt++)
                #pragma unroll
                for (int nt = 0; nt < 2; nt++)
                    acc[mt][nt] = MFMAH(a[mt], b[nt], acc[mt][nt]);
        }
        __syncthreads();
        buf ^= 1;
    }
#undef STAGE

    #pragma unroll
    for (int mt = 0; mt < 4; mt++) {
        #pragma unroll
        for (int nt = 0; nt < 2; nt++) {
            int n = n0 + wc * 32 + nt * 16 + l15;
            float bv = bias[n];
            #pragma unroll
            for (int r = 0; r < 4; r++) {
                int m = m0 + wr * 64 + mt * 16 + quad * 4 + r;
                out[(size_t)m * 1024 + n] = acc[mt][nt][r] + bv;
            }
        }
    }
}

// ---------------------------------------------------------------------------
extern "C" void kernel_launch(void* const* d_in, const int* in_sizes, int n_in,
                              void* d_out, int out_size, void* d_ws, size_t ws_size,
                              hipStream_t stream) {
    const float* x  = (const float*)d_in[0];
    const float* Wq = (const float*)d_in[1];
    const float* bq = (const float*)d_in[2];
    const float* Wk = (const float*)d_in[3];
    const float* bk = (const float*)d_in[4];
    const float* Wv = (const float*)d_in[5];
    const float* bv = (const float*)d_in[6];
    const float* Wo = (const float*)d_in[7];
    const float* bo = (const float*)d_in[8];
    float* out = (float*)d_out;

    const size_t TEN = (size_t)MROWS * KDIM;     // 4,194,304
    const size_t WSZ = (size_t)KDIM * KDIM;      // 1,048,576

    u16* xF  = (u16*)d_ws;
    u16* WqF = xF + TEN;
    u16* WkF = WqF + WSZ;
    u16* WvF = WkF + WSZ;
    u16* WoF = WvF + WSZ;
    u16* QF  = WoF + WSZ;
    u16* KF  = QF + TEN;
    u16* VtF = KF + TEN;
    float* km2 = (float*)(VtF + TEN);
    float2* ropeT = (float2*)(km2 + 4);          // 2048*32 float2 = 512 KB
    u16* AOF = xF;          // x dead after qkv_gemm

    convert_f16<<<4352, 256, 0, stream>>>(x, Wq, Wk, Wv, Wo,
                                          xF, WqF, WkF, WvF, WoF, ropeT);

    hipMemsetAsync(km2, 0, 4, stream);

    qkv_gemm<<<768, 256, 0, stream>>>(xF, WqF, WkF, WvF,
                                      bq, bk, bv, ropeT, QF, KF, VtF, km2);

    flash_attn<<<1024, 256, 0, stream>>>(QF, KF, VtF, km2, AOF);

    gemm_out<<<512, 256, 0, stream>>>(AOF, WoF, bo, out);
}

// Round 10
// 208.763 us; speedup vs baseline: 1.0191x; 1.0191x over previous
//
#include <hip/hip_runtime.h>
#include <hip/hip_fp16.h>
#include <math.h>

#define D_MODEL 1024
#define NH 16
#define HD 64
#define SEQ 2048
#define BATCH 2
#define MROWS (BATCH*SEQ)   // 4096
#define KDIM 1024

typedef unsigned short u16;
typedef __attribute__((ext_vector_type(8))) _Float16 h8;   // 8 f16 (4 VGPRs)
typedef __attribute__((ext_vector_type(8))) short s8v;
typedef __attribute__((ext_vector_type(4))) float f4v;

#define MFMAH(a, b, c) __builtin_amdgcn_mfma_f32_16x16x32_f16(a, b, c, 0, 0, 0)

// async global->LDS DMA, 16B/lane; LDS dest must be wave-uniform base
__device__ __forceinline__ void gld16(const u16* g, u16* l) {
    __builtin_amdgcn_global_load_lds(
        (const __attribute__((address_space(1))) void*)g,
        (__attribute__((address_space(3))) void*)l, 16, 0, 0);
}

__device__ __forceinline__ u16 f32_to_f16(float f) {
    return __half_as_ushort(__float2half(f));   // v_cvt_f16_f32, RNE
}

// ---------------------------------------------------------------------------
// fp32 -> fp16 conversion for x (4M) + 4 W (1M each), 8 elems/thread, PLUS
// RoPE cos/sin table build (blocks 4096..4351): ropeT[s*32+dd].
// ---------------------------------------------------------------------------
__global__ __launch_bounds__(256)
void convert_f16(const float* __restrict__ x,
                 const float* __restrict__ Wq, const float* __restrict__ Wk,
                 const float* __restrict__ Wv, const float* __restrict__ Wo,
                 u16* __restrict__ xF,
                 u16* __restrict__ WqF, u16* __restrict__ WkF,
                 u16* __restrict__ WvF, u16* __restrict__ WoF,
                 float2* __restrict__ ropeT) {
    int i = blockIdx.x * 256 + threadIdx.x;
    if (i >= (1 << 20)) {
        // ---- RoPE table: s in [0,2048), dd in [0,32) ----
        int idx2 = i - (1 << 20);          // 0..65535
        int s  = idx2 >> 5;
        int dd = idx2 & 31;
        float inv = __expf(-(float)dd * 0.2878231366f);   // 1e4^(-dd/32)
        float ang = (float)s * inv;
        ropeT[idx2] = make_float2(cosf(ang), sinf(ang));  // same math as before
        return;
    }
    const float* src;
    u16* dst;
    int idx;
    if (i < (1 << 19)) {
        src = x; dst = xF; idx = i;
    } else {
        int j = i - (1 << 19);
        int w = j >> 17;
        idx = j & ((1 << 17) - 1);
        switch (w) {
            case 0:  src = Wq; dst = WqF; break;
            case 1:  src = Wk; dst = WkF; break;
            case 2:  src = Wv; dst = WvF; break;
            default: src = Wo; dst = WoF; break;
        }
    }
    float4 a = ((const float4*)src)[idx * 2];
    float4 b = ((const float4*)src)[idx * 2 + 1];
    s8v o;
    o[0] = (short)f32_to_f16(a.x); o[1] = (short)f32_to_f16(a.y);
    o[2] = (short)f32_to_f16(a.z); o[3] = (short)f32_to_f16(a.w);
    o[4] = (short)f32_to_f16(b.x); o[5] = (short)f32_to_f16(b.y);
    o[6] = (short)f32_to_f16(b.z); o[7] = (short)f32_to_f16(b.w);
    ((s8v*)dst)[idx] = o;
}

// ---------------------------------------------------------------------------
// Fused QKV fp16 MFMA GEMM — BM=128 BN=128 BK=64, 64KB LDS dbuf,
// 2 blocks/CU. global_load_lds w=16, source-side XOR swizzle. Grid 768.
// Q,K: fused RoPE (table) -> LDS-staged full-line stores. K: atomicMax
// row-norm^2. V: LDS transpose -> fp16 [B,H,D,S].  (unchanged from R8)
// ---------------------------------------------------------------------------
__global__ __launch_bounds__(256, 2)
void qkv_gemm(const u16* __restrict__ xF, const u16* __restrict__ WqF,
              const u16* __restrict__ WkF, const u16* __restrict__ WvF,
              const float* __restrict__ bq, const float* __restrict__ bk,
              const float* __restrict__ bv,
              const float2* __restrict__ ropeT,
              u16* __restrict__ QF, u16* __restrict__ KF,
              u16* __restrict__ VtF, float* __restrict__ km2) {
    __shared__ __align__(16) u16 SMEM[32768];   // 64 KB

    const int t    = threadIdx.x;
    const int w    = t >> 6;
    const int lane = t & 63;
    const int quad = lane >> 4;
    const int l15  = lane & 15;
    const int wr   = w >> 1;
    const int wc   = w & 1;

    const int bid  = blockIdx.x;
    const int xcd  = bid & 7;
    const int j    = bid >> 3;          // 0..95
    const int m0   = (xcd * 4 + (j & 3)) * 128;
    const int yt   = j >> 2;            // 0..23
    const int wsel = yt >> 3;
    const int n0   = (yt & 7) * 128;

    const u16* Bg;
    const float* bias;
    if (wsel == 0)      { Bg = WqF; bias = bq; }
    else if (wsel == 1) { Bg = WkF; bias = bk; }
    else                { Bg = WvF; bias = bv; }

    const int lr = lane >> 3;                 // row within seg
    const int lc = (((lane & 7) ^ lr)) * 8;   // swizzled global u16 col

    f4v acc[4][4];
    #pragma unroll
    for (int i = 0; i < 4; i++)
        #pragma unroll
        for (int jj = 0; jj < 4; jj++)
            acc[i][jj] = (f4v){0.f, 0.f, 0.f, 0.f};

#define STAGE(K0, DB) do {                                                   \
    u16* As_ = SMEM + (DB);                                                  \
    u16* Bs_ = As_ + 8192;                                                   \
    _Pragma("unroll")                                                        \
    for (int jj_ = 0; jj_ < 4; jj_++) {                                      \
        int seg = jj_ * 4 + w;                                               \
        gld16(xF + (size_t)(m0 + seg * 8 + lr) * KDIM + (K0) + lc,           \
              As_ + seg * 512);                                              \
        gld16(Bg + (size_t)(n0 + seg * 8 + lr) * KDIM + (K0) + lc,           \
              Bs_ + seg * 512);                                              \
    }                                                                        \
} while (0)

    STAGE(0, 0);
    __syncthreads();

    int buf = 0;
    for (int k0 = 0; k0 < KDIM; k0 += 64) {
        if (k0 + 64 < KDIM) STAGE(k0 + 64, (buf ^ 1) * 16384);

        const u16* As = SMEM + buf * 16384;
        const u16* Bs = As + 8192;
        #pragma unroll
        for (int kk = 0; kk < 2; kk++) {
            const int swz = ((kk * 4 + quad) ^ (l15 & 7)) << 3;
            h8 a[4], b[4];
            #pragma unroll
            for (int mt = 0; mt < 4; mt++)
                a[mt] = *(const h8*)&As[(wr * 64 + mt * 16 + l15) * 64 + swz];
            #pragma unroll
            for (int nt = 0; nt < 4; nt++)
                b[nt] = *(const h8*)&Bs[(wc * 64 + nt * 16 + l15) * 64 + swz];
            #pragma unroll
            for (int mt = 0; mt < 4; mt++)
                #pragma unroll
                for (int nt = 0; nt < 4; nt++)
                    acc[mt][nt] = MFMAH(a[mt], b[nt], acc[mt][nt]);
        }
        __syncthreads();
        buf ^= 1;
    }
#undef STAGE

    const int bb = m0 >> 11;
    const int s0 = m0 & 2047;
    const int h0 = n0 >> 6;             // first of 2 heads in this n-tile

    if (wsel < 2) {
        // ---- Q/K: fused RoPE (table) -> LDS tile [128 s][128 n] swizzled ----
        u16* OF = (wsel == 0) ? QF : KF;
        float kn_max = 0.f;
        #pragma unroll
        for (int mt = 0; mt < 4; mt++) {
            #pragma unroll
            for (int r = 0; r < 4; r++) {
                int R = wr * 64 + mt * 16 + quad * 4 + r;     // local s
                int s = s0 + R;
                float rowsum = 0.f;
                #pragma unroll
                for (int nt = 0; nt < 2; nt++) {
                    int col = wc * 64 + nt * 16 + l15;        // local n
                    int n1 = n0 + col;
                    int dd = n1 & 31;
                    float v1 = acc[mt][nt][r]     + bias[n1];
                    float v2 = acc[mt][nt + 2][r] + bias[n1 + 32];
                    float2 cssn = ropeT[(s << 5) | dd];       // coalesced
                    float cs  = cssn.x;
                    float sn  = cssn.y;
                    float r1 = v1 * cs - v2 * sn;
                    float r2 = v2 * cs + v1 * sn;
                    rowsum += v1 * v1 + v2 * v2;     // norm is RoPE-invariant
                    SMEM[R * 128 + (((col >> 3) ^ (R & 15)) << 3) + (col & 7)]
                        = f32_to_f16(r1);
                    int col2 = col + 32;
                    SMEM[R * 128 + (((col2 >> 3) ^ (R & 15)) << 3) + (col2 & 7)]
                        = f32_to_f16(r2);
                }
                if (wsel == 1) {
                    rowsum += __shfl_xor(rowsum, 1, 64);
                    rowsum += __shfl_xor(rowsum, 2, 64);
                    rowsum += __shfl_xor(rowsum, 4, 64);
                    rowsum += __shfl_xor(rowsum, 8, 64);
                    kn_max = fmaxf(kn_max, rowsum);
                }
            }
        }
        if (wsel == 1) {
            kn_max = fmaxf(kn_max, __shfl_xor(kn_max, 16, 64));
            kn_max = fmaxf(kn_max, __shfl_xor(kn_max, 32, 64));
            if (lane == 0) atomicMax((int*)km2, __float_as_int(kn_max));
        }
        __syncthreads();
        // drain: per instruction each wave writes 1 KB contiguous [B,H,S,D]
        #pragma unroll
        for (int cc = 0; cc < 8; cc++) {
            int idx  = cc * 256 + t;       // 0..2047
            int hl   = idx >> 10;          // 0..1
            int rem  = idx & 1023;
            int R    = rem >> 3;           // local s 0..127
            int dch  = rem & 7;            // 16B chunk along d
            s8v val = *(const s8v*)&SMEM[R * 128 +
                          (((hl * 8 + dch) ^ (R & 15)) << 3)];
            *(s8v*)(OF + (((size_t)bb * NH + h0 + hl) * SEQ + s0 + R) * 64
                       + dch * 8) = val;
        }
    } else {
        // ---- V: transpose via LDS [128 n][128 m], fp16 [B,H,D,S] ----
        #pragma unroll
        for (int mt = 0; mt < 4; mt++) {
            #pragma unroll
            for (int nt = 0; nt < 4; nt++) {
                int n = wc * 64 + nt * 16 + l15;
                float bv_ = bias[n0 + n];
                #pragma unroll
                for (int r = 0; r < 4; r++) {
                    int m = wr * 64 + mt * 16 + quad * 4 + r;
                    float v = acc[mt][nt][r] + bv_;
                    SMEM[n * 128 + (((m >> 3) ^ (n & 15)) << 3) + (m & 7)]
                        = f32_to_f16(v);
                }
            }
        }
        __syncthreads();
        // drain: per instruction a wave covers 4 full d-rows (4 x 256B)
        #pragma unroll
        for (int cc = 0; cc < 8; cc++) {
            int idx = cc * 256 + t;        // 0..2047
            int n   = idx >> 4;            // local col: h*64+d, 0..127
            int mc  = idx & 15;            // 16B chunk along s
            int d   = n & 63;
            int hh  = n >> 6;
            size_t obase = ((size_t)((bb * NH + h0 + hh) * HD + d)) * SEQ + s0;
            s8v val = *(const s8v*)&SMEM[n * 128 + ((mc ^ (n & 15)) << 3)];
            *(s8v*)(VtF + obase + mc * 8) = val;
        }
    }
}

// ---------------------------------------------------------------------------
// MFMA flash attention, Q-tile 64, grid 1024 (4 blocks/CU). Round-10:
// exact R8 structure (KVBLK=64 — R9's KVBLK=128 + ocml exp2f regressed via
// precise-exp2f fixup code, VALUBusy 37->53%). Single change vs R8: exp
// fold via RAW v_exp_f32 builtin (__builtin_amdgcn_exp2f), log2e pre-folded
// into scale C1 and bound mb2 — 8 v_mul/subtile removed, no libcall.
// Swapped QK^T with key-permuted staging; P in registers (R8-verified).
// ---------------------------------------------------------------------------
__global__ __launch_bounds__(256, 4)
void flash_attn(const u16* __restrict__ QF, const u16* __restrict__ KF,
                const u16* __restrict__ VtF,
                const float* __restrict__ kmax2,
                u16* __restrict__ AOF) {
    __shared__ __align__(16) u16 KS[2][32 * 72];
    __shared__ __align__(16) u16 VtS[2][64 * 40];

    const int t    = threadIdx.x;
    const int w    = t >> 6;
    const int lane = t & 63;
    const int quad = lane >> 4;
    const int l15  = lane & 15;

    const int bid = blockIdx.x;
    const int xcd = bid & 7;
    const int j   = bid >> 3;          // 0..127
    const int bh  = xcd * 4 + (j & 3); // 0..31
    const int q0  = (j >> 2) * 64;     // 0..31 * 64

    const size_t kvbase = (size_t)bh * SEQ * HD;
    const float km2 = kmax2[0];
    const float C1 = 0.125f * 1.44269504089f;   // scale * log2(e)

    // ---- Q fragments; static softmax bound (log2 domain) for q-row l15 ----
    h8 qf[2];
    float mb2;
    {
        const u16* qp = QF + kvbase +
            (size_t)(q0 + w * 16 + l15) * HD + quad * 8;
        qf[0] = *(const h8*)qp;
        qf[1] = *(const h8*)(qp + 32);
        float qn2 = 0.f;
        #pragma unroll
        for (int st = 0; st < 2; st++)
            #pragma unroll
            for (int e = 0; e < 8; e++) {
                float v = (float)qf[st][e];
                qn2 += v * v;
            }
        qn2 += __shfl_xor(qn2, 16, 64);
        qn2 += __shfl_xor(qn2, 32, 64);   // row norm^2, replicated over quads
        mb2 = sqrtf(qn2 * km2) * C1;      // bound in log2 domain
    }

    f4v o[4];
    #pragma unroll
    for (int nt = 0; nt < 4; nt++) o[nt] = (f4v){0.f, 0.f, 0.f, 0.f};
    float lsum = 0.f;

    // ---- staging addresses; K rows permuted: phys row krow holds key pkey ----
    const int krow = t >> 3;                 // physical LDS row 0..31
    const int kdc  = (t & 7) * 8;            // 16B chunk along d
    const int pkey = (krow & 3) + 8 * ((krow >> 2) & 3) + 4 * (krow >> 4);
    const u16* kgp = KF + kvbase + (size_t)pkey * HD + kdc;
    const int vd   = t >> 2;                 // 0..63
    const int vkc  = (t & 3) * 8;            // 16B chunk along keys
    const int vcol = vkc ^ (((vd >> 3) & 3) << 3);
    const u16* vgp = VtF + (size_t)bh * HD * SEQ + (size_t)vd * SEQ + vkc;

    // prologue: prefetch tile 0 into registers
    s8v krg0 = *(const s8v*)(kgp);
    s8v krg1 = *(const s8v*)(kgp + (size_t)32 * HD);
    s8v vrg0 = *(const s8v*)(vgp);
    s8v vrg1 = *(const s8v*)(vgp + 32);

    for (int k0 = 0; k0 < SEQ; k0 += 64) {
        __syncthreads();                     // prev compute's LDS reads done
        *(s8v*)&KS[0][krow * 72 + kdc] = krg0;
        *(s8v*)&KS[1][krow * 72 + kdc] = krg1;
        *(s8v*)&VtS[0][vd * 40 + vcol] = vrg0;
        *(s8v*)&VtS[1][vd * 40 + vcol] = vrg1;
        if (k0 + 64 < SEQ) {
            const u16* kn = kgp + (size_t)(k0 + 64) * HD;
            krg0 = *(const s8v*)(kn);
            krg1 = *(const s8v*)(kn + (size_t)32 * HD);
            vrg0 = *(const s8v*)(vgp + k0 + 64);
            vrg1 = *(const s8v*)(vgp + k0 + 96);
        }
        __syncthreads();

        #pragma unroll
        for (int sub = 0; sub < 2; sub++) {
            // phys rows l15 / 16+l15 = key groups {a+8b} / {a+8b+4}
            const u16* kb0 = KS[sub] + l15 * 72 + quad * 8;
            const u16* kb1 = KS[sub] + (16 + l15) * 72 + quad * 8;
            h8 kh0 = *(const h8*)kb0, kh1 = *(const h8*)(kb0 + 32);
            h8 kh2 = *(const h8*)kb1, kh3 = *(const h8*)(kb1 + 32);

            // S^T = K·Q^T: lane(l15,quad) reg r = S[q=l15][key 8*quad+r (+4)]
            f4v sc0 = (f4v){0.f, 0.f, 0.f, 0.f};
            f4v sc1 = (f4v){0.f, 0.f, 0.f, 0.f};
            __builtin_amdgcn_s_setprio(1);
            sc0 = MFMAH(kh0, qf[0], sc0);
            sc0 = MFMAH(kh1, qf[1], sc0);
            sc1 = MFMAH(kh2, qf[0], sc1);
            sc1 = MFMAH(kh3, qf[1], sc1);
            __builtin_amdgcn_s_setprio(0);

            // in-register softmax (log2 domain, raw v_exp_f32):
            // 8 P values for q=l15, keys 8q..8q+7
            float p[8];
            #pragma unroll
            for (int r = 0; r < 4; r++) {
                p[r]     = __builtin_amdgcn_exp2f(sc0[r] * C1 - mb2);
                p[4 + r] = __builtin_amdgcn_exp2f(sc1[r] * C1 - mb2);
            }
            lsum += ((p[0] + p[1]) + (p[2] + p[3]))
                  + ((p[4] + p[5]) + (p[6] + p[7]));

            // pack to PV B-fragment: slots 0..7 = keys 8q..8q+7
            h8 pb;
            __half2* pp = (__half2*)&pb;
            pp[0] = __floats2half2_rn(p[0], p[1]);
            pp[1] = __floats2half2_rn(p[2], p[3]);
            pp[2] = __floats2half2_rn(p[4], p[5]);
            pp[3] = __floats2half2_rn(p[6], p[7]);

            // O^T += V^T·P^T (V read identical: A/B layout equivalence)
            __builtin_amdgcn_s_setprio(1);
            #pragma unroll
            for (int nt = 0; nt < 4; nt++) {
                int dim = nt * 16 + l15;
                int voff = dim * 40 + ((quad * 8) ^ (((dim >> 3) & 3) << 3));
                o[nt] = MFMAH(*(const h8*)&VtS[sub][voff], pb, o[nt]);
            }
            __builtin_amdgcn_s_setprio(0);
        }
    }

    // ---- epilogue: reduce l over quads, normalize, LDS transpose, store ----
    lsum += __shfl_xor(lsum, 16, 64);
    lsum += __shfl_xor(lsum, 32, 64);
    float inv_l = 1.0f / lsum;

    const int b = bh >> 4;
    const int h = bh & 15;
    u16* OS = &KS[0][0];                 // 8 KB, aliases dead K tiles
    __syncthreads();                     // all waves done reading KS
    const int srow = w * 16 + l15;       // local s 0..63
    #pragma unroll
    for (int nt = 0; nt < 4; nt++) {
        #pragma unroll
        for (int r = 0; r < 4; r++) {
            int d = nt * 16 + quad * 4 + r;
            OS[srow * 64 + (((d >> 3) ^ (srow & 7)) << 3) + (d & 7)]
                = f32_to_f16(o[nt][r] * inv_l);
        }
    }
    __syncthreads();
    // per instruction: wave covers 8 full 128B lines of [B,S,H,D]
    #pragma unroll
    for (int cc = 0; cc < 2; cc++) {
        int idx = cc * 256 + t;          // 0..511
        int sr  = idx >> 3;              // 0..63
        int dch = idx & 7;
        s8v val = *(const s8v*)&OS[sr * 64 + ((dch ^ (sr & 7)) << 3)];
        *(s8v*)(AOF + (((size_t)b * SEQ + q0 + sr) * NH + h) * HD + dch * 8)
            = val;
    }
}

// ---------------------------------------------------------------------------
// Out-projection fp16 MFMA GEMM — BM=128 BN=64 BK=64, grid 512 (unchanged).
// ---------------------------------------------------------------------------
__global__ __launch_bounds__(256, 2)
void gemm_out(const u16* __restrict__ AF, const u16* __restrict__ BF,
              const float* __restrict__ bias, float* __restrict__ out) {
    __shared__ __align__(16) u16 SMEM[24576];   // 48 KB

    const int t    = threadIdx.x;
    const int w    = t >> 6;
    const int lane = t & 63;
    const int quad = lane >> 4;
    const int l15  = lane & 15;
    const int wr   = w >> 1;        // m-half (64 rows)
    const int wc   = w & 1;         // n-half (32 cols)

    const int bid = blockIdx.x;
    const int xcd = bid & 7;
    const int j   = bid >> 3;              // 0..63
    const int m0  = (xcd * 4 + (j & 3)) * 128;
    const int n0  = (j >> 2) * 64;         // 0..15 * 64

    const int lr = lane >> 3;
    const int lc = (((lane & 7) ^ lr)) * 8;

    f4v acc[4][2];
    #pragma unroll
    for (int i = 0; i < 4; i++)
        #pragma unroll
        for (int jj = 0; jj < 2; jj++)
            acc[i][jj] = (f4v){0.f, 0.f, 0.f, 0.f};

#define STAGE(K0, DB) do {                                                   \
    u16* As_ = SMEM + (DB);                                                  \
    u16* Bs_ = As_ + 8192;                                                   \
    _Pragma("unroll")                                                        \
    for (int jj_ = 0; jj_ < 4; jj_++) {                                      \
        int seg = jj_ * 4 + w;                                               \
        gld16(AF + (size_t)(m0 + seg * 8 + lr) * KDIM + (K0) + lc,           \
              As_ + seg * 512);                                              \
    }                                                                        \
    _Pragma("unroll")                                                        \
    for (int jj_ = 0; jj_ < 2; jj_++) {                                      \
        int seg = jj_ * 4 + w;                                               \
        gld16(BF + (size_t)(n0 + seg * 8 + lr) * KDIM + (K0) + lc,           \
              Bs_ + seg * 512);                                              \
    }                                                                        \
} while (0)

    STAGE(0, 0);
    __syncthreads();

    int buf = 0;
    for (int k0 = 0; k0 < KDIM; k0 += 64) {
        if (k0 + 64 < KDIM) STAGE(k0 + 64, (buf ^ 1) * 12288);

        const u16* As = SMEM + buf * 12288;
        const u16* Bs = As + 8192;
        #pragma unroll
        for (int kk = 0; kk < 2; kk++) {
            const int swz = ((kk * 4 + quad) ^ (l15 & 7)) << 3;
            h8 a[4], b[2];
            #pragma unroll
            for (int mt = 0; mt < 4; mt++)
                a[mt] = *(const h8*)&As[(wr * 64 + mt * 16 + l15) * 64 + swz];
            #pragma unroll
            for (int nt = 0; nt < 2; nt++)
                b[nt] = *(const h8*)&Bs[(wc * 32 + nt * 16 + l15) * 64 + swz];
            #pragma unroll
            for (int mt = 0; mt < 4; mt++)
                #pragma unroll
                for (int nt = 0; nt < 2; nt++)
                    acc[mt][nt] = MFMAH(a[mt], b[nt], acc[mt][nt]);
        }
        __syncthreads();
        buf ^= 1;
    }
#undef STAGE

    #pragma unroll
    for (int mt = 0; mt < 4; mt++) {
        #pragma unroll
        for (int nt = 0; nt < 2; nt++) {
            int n = n0 + wc * 32 + nt * 16 + l15;
            float bv = bias[n];
            #pragma unroll
            for (int r = 0; r < 4; r++) {
                int m = m0 + wr * 64 + mt * 16 + quad * 4 + r;
                out[(size_t)m * 1024 + n] = acc[mt][nt][r] + bv;
            }
        }
    }
}

// ---------------------------------------------------------------------------
extern "C" void kernel_launch(void* const* d_in, const int* in_sizes, int n_in,
                              void* d_out, int out_size, void* d_ws, size_t ws_size,
                              hipStream_t stream) {
    const float* x  = (const float*)d_in[0];
    const float* Wq = (const float*)d_in[1];
    const float* bq = (const float*)d_in[2];
    const float* Wk = (const float*)d_in[3];
    const float* bk = (const float*)d_in[4];
    const float* Wv = (const float*)d_in[5];
    const float* bv = (const float*)d_in[6];
    const float* Wo = (const float*)d_in[7];
    const float* bo = (const float*)d_in[8];
    float* out = (float*)d_out;

    const size_t TEN = (size_t)MROWS * KDIM;     // 4,194,304
    const size_t WSZ = (size_t)KDIM * KDIM;      // 1,048,576

    u16* xF  = (u16*)d_ws;
    u16* WqF = xF + TEN;
    u16* WkF = WqF + WSZ;
    u16* WvF = WkF + WSZ;
    u16* WoF = WvF + WSZ;
    u16* QF  = WoF + WSZ;
    u16* KF  = QF + TEN;
    u16* VtF = KF + TEN;
    float* km2 = (float*)(VtF + TEN);
    float2* ropeT = (float2*)(km2 + 4);          // 2048*32 float2 = 512 KB
    u16* AOF = xF;          // x dead after qkv_gemm

    convert_f16<<<4352, 256, 0, stream>>>(x, Wq, Wk, Wv, Wo,
                                          xF, WqF, WkF, WvF, WoF, ropeT);

    hipMemsetAsync(km2, 0, 4, stream);

    qkv_gemm<<<768, 256, 0, stream>>>(xF, WqF, WkF, WvF,
                                      bq, bk, bv, ropeT, QF, KF, VtF, km2);

    flash_attn<<<1024, 256, 0, stream>>>(QF, KF, VtF, km2, AOF);

    gemm_out<<<512, 256, 0, stream>>>(AOF, WoF, bo, out);
}

// Round 11
// 198.941 us; speedup vs baseline: 1.0695x; 1.0494x over previous
//
#include <hip/hip_runtime.h>
#include <hip/hip_fp16.h>
#include <math.h>

#define D_MODEL 1024
#define NH 16
#define HD 64
#define SEQ 2048
#define BATCH 2
#define MROWS (BATCH*SEQ)   // 4096
#define KDIM 1024

typedef unsigned short u16;
typedef __attribute__((ext_vector_type(8))) _Float16 h8;   // 8 f16 (4 VGPRs)
typedef __attribute__((ext_vector_type(8))) short s8v;
typedef __attribute__((ext_vector_type(4))) float f4v;

#define MFMAH(a, b, c) __builtin_amdgcn_mfma_f32_16x16x32_f16(a, b, c, 0, 0, 0)

// async global->LDS DMA, 16B/lane; LDS dest must be wave-uniform base
__device__ __forceinline__ void gld16(const u16* g, u16* l) {
    __builtin_amdgcn_global_load_lds(
        (const __attribute__((address_space(1))) void*)g,
        (__attribute__((address_space(3))) void*)l, 16, 0, 0);
}

__device__ __forceinline__ u16 f32_to_f16(float f) {
    return __half_as_ushort(__float2half(f));   // v_cvt_f16_f32, RNE
}

// ---------------------------------------------------------------------------
// fp32 -> fp16 conversion for x (4M) + 4 W (1M each), 8 elems/thread, PLUS
// RoPE cos/sin table build (blocks 4096..4351): ropeT[s*32+dd].
// ---------------------------------------------------------------------------
__global__ __launch_bounds__(256)
void convert_f16(const float* __restrict__ x,
                 const float* __restrict__ Wq, const float* __restrict__ Wk,
                 const float* __restrict__ Wv, const float* __restrict__ Wo,
                 u16* __restrict__ xF,
                 u16* __restrict__ WqF, u16* __restrict__ WkF,
                 u16* __restrict__ WvF, u16* __restrict__ WoF,
                 float2* __restrict__ ropeT) {
    int i = blockIdx.x * 256 + threadIdx.x;
    if (i >= (1 << 20)) {
        // ---- RoPE table: s in [0,2048), dd in [0,32) ----
        int idx2 = i - (1 << 20);          // 0..65535
        int s  = idx2 >> 5;
        int dd = idx2 & 31;
        float inv = __expf(-(float)dd * 0.2878231366f);   // 1e4^(-dd/32)
        float ang = (float)s * inv;
        ropeT[idx2] = make_float2(cosf(ang), sinf(ang));  // same math as before
        return;
    }
    const float* src;
    u16* dst;
    int idx;
    if (i < (1 << 19)) {
        src = x; dst = xF; idx = i;
    } else {
        int j = i - (1 << 19);
        int w = j >> 17;
        idx = j & ((1 << 17) - 1);
        switch (w) {
            case 0:  src = Wq; dst = WqF; break;
            case 1:  src = Wk; dst = WkF; break;
            case 2:  src = Wv; dst = WvF; break;
            default: src = Wo; dst = WoF; break;
        }
    }
    float4 a = ((const float4*)src)[idx * 2];
    float4 b = ((const float4*)src)[idx * 2 + 1];
    s8v o;
    o[0] = (short)f32_to_f16(a.x); o[1] = (short)f32_to_f16(a.y);
    o[2] = (short)f32_to_f16(a.z); o[3] = (short)f32_to_f16(a.w);
    o[4] = (short)f32_to_f16(b.x); o[5] = (short)f32_to_f16(b.y);
    o[6] = (short)f32_to_f16(b.z); o[7] = (short)f32_to_f16(b.w);
    ((s8v*)dst)[idx] = o;
}

// ---------------------------------------------------------------------------
// Fused QKV fp16 MFMA GEMM — BM=128 BN=128 BK=64, 64KB LDS dbuf,
// 2 blocks/CU. global_load_lds w=16, source-side XOR swizzle. Grid 768.
// Q,K: fused RoPE (table) -> LDS-staged full-line stores. K: atomicMax
// row-norm^2. V: LDS transpose -> fp16 [B,H,D,S].  (unchanged from R8)
// ---------------------------------------------------------------------------
__global__ __launch_bounds__(256, 2)
void qkv_gemm(const u16* __restrict__ xF, const u16* __restrict__ WqF,
              const u16* __restrict__ WkF, const u16* __restrict__ WvF,
              const float* __restrict__ bq, const float* __restrict__ bk,
              const float* __restrict__ bv,
              const float2* __restrict__ ropeT,
              u16* __restrict__ QF, u16* __restrict__ KF,
              u16* __restrict__ VtF, float* __restrict__ km2) {
    __shared__ __align__(16) u16 SMEM[32768];   // 64 KB

    const int t    = threadIdx.x;
    const int w    = t >> 6;
    const int lane = t & 63;
    const int quad = lane >> 4;
    const int l15  = lane & 15;
    const int wr   = w >> 1;
    const int wc   = w & 1;

    const int bid  = blockIdx.x;
    const int xcd  = bid & 7;
    const int j    = bid >> 3;          // 0..95
    const int m0   = (xcd * 4 + (j & 3)) * 128;
    const int yt   = j >> 2;            // 0..23
    const int wsel = yt >> 3;
    const int n0   = (yt & 7) * 128;

    const u16* Bg;
    const float* bias;
    if (wsel == 0)      { Bg = WqF; bias = bq; }
    else if (wsel == 1) { Bg = WkF; bias = bk; }
    else                { Bg = WvF; bias = bv; }

    const int lr = lane >> 3;                 // row within seg
    const int lc = (((lane & 7) ^ lr)) * 8;   // swizzled global u16 col

    f4v acc[4][4];
    #pragma unroll
    for (int i = 0; i < 4; i++)
        #pragma unroll
        for (int jj = 0; jj < 4; jj++)
            acc[i][jj] = (f4v){0.f, 0.f, 0.f, 0.f};

#define STAGE(K0, DB) do {                                                   \
    u16* As_ = SMEM + (DB);                                                  \
    u16* Bs_ = As_ + 8192;                                                   \
    _Pragma("unroll")                                                        \
    for (int jj_ = 0; jj_ < 4; jj_++) {                                      \
        int seg = jj_ * 4 + w;                                               \
        gld16(xF + (size_t)(m0 + seg * 8 + lr) * KDIM + (K0) + lc,           \
              As_ + seg * 512);                                              \
        gld16(Bg + (size_t)(n0 + seg * 8 + lr) * KDIM + (K0) + lc,           \
              Bs_ + seg * 512);                                              \
    }                                                                        \
} while (0)

    STAGE(0, 0);
    __syncthreads();

    int buf = 0;
    for (int k0 = 0; k0 < KDIM; k0 += 64) {
        if (k0 + 64 < KDIM) STAGE(k0 + 64, (buf ^ 1) * 16384);

        const u16* As = SMEM + buf * 16384;
        const u16* Bs = As + 8192;
        #pragma unroll
        for (int kk = 0; kk < 2; kk++) {
            const int swz = ((kk * 4 + quad) ^ (l15 & 7)) << 3;
            h8 a[4], b[4];
            #pragma unroll
            for (int mt = 0; mt < 4; mt++)
                a[mt] = *(const h8*)&As[(wr * 64 + mt * 16 + l15) * 64 + swz];
            #pragma unroll
            for (int nt = 0; nt < 4; nt++)
                b[nt] = *(const h8*)&Bs[(wc * 64 + nt * 16 + l15) * 64 + swz];
            #pragma unroll
            for (int mt = 0; mt < 4; mt++)
                #pragma unroll
                for (int nt = 0; nt < 4; nt++)
                    acc[mt][nt] = MFMAH(a[mt], b[nt], acc[mt][nt]);
        }
        __syncthreads();
        buf ^= 1;
    }
#undef STAGE

    const int bb = m0 >> 11;
    const int s0 = m0 & 2047;
    const int h0 = n0 >> 6;             // first of 2 heads in this n-tile

    if (wsel < 2) {
        // ---- Q/K: fused RoPE (table) -> LDS tile [128 s][128 n] swizzled ----
        u16* OF = (wsel == 0) ? QF : KF;
        float kn_max = 0.f;
        #pragma unroll
        for (int mt = 0; mt < 4; mt++) {
            #pragma unroll
            for (int r = 0; r < 4; r++) {
                int R = wr * 64 + mt * 16 + quad * 4 + r;     // local s
                int s = s0 + R;
                float rowsum = 0.f;
                #pragma unroll
                for (int nt = 0; nt < 2; nt++) {
                    int col = wc * 64 + nt * 16 + l15;        // local n
                    int n1 = n0 + col;
                    int dd = n1 & 31;
                    float v1 = acc[mt][nt][r]     + bias[n1];
                    float v2 = acc[mt][nt + 2][r] + bias[n1 + 32];
                    float2 cssn = ropeT[(s << 5) | dd];       // coalesced
                    float cs  = cssn.x;
                    float sn  = cssn.y;
                    float r1 = v1 * cs - v2 * sn;
                    float r2 = v2 * cs + v1 * sn;
                    rowsum += v1 * v1 + v2 * v2;     // norm is RoPE-invariant
                    SMEM[R * 128 + (((col >> 3) ^ (R & 15)) << 3) + (col & 7)]
                        = f32_to_f16(r1);
                    int col2 = col + 32;
                    SMEM[R * 128 + (((col2 >> 3) ^ (R & 15)) << 3) + (col2 & 7)]
                        = f32_to_f16(r2);
                }
                if (wsel == 1) {
                    rowsum += __shfl_xor(rowsum, 1, 64);
                    rowsum += __shfl_xor(rowsum, 2, 64);
                    rowsum += __shfl_xor(rowsum, 4, 64);
                    rowsum += __shfl_xor(rowsum, 8, 64);
                    kn_max = fmaxf(kn_max, rowsum);
                }
            }
        }
        if (wsel == 1) {
            kn_max = fmaxf(kn_max, __shfl_xor(kn_max, 16, 64));
            kn_max = fmaxf(kn_max, __shfl_xor(kn_max, 32, 64));
            if (lane == 0) atomicMax((int*)km2, __float_as_int(kn_max));
        }
        __syncthreads();
        // drain: per instruction each wave writes 1 KB contiguous [B,H,S,D]
        #pragma unroll
        for (int cc = 0; cc < 8; cc++) {
            int idx  = cc * 256 + t;       // 0..2047
            int hl   = idx >> 10;          // 0..1
            int rem  = idx & 1023;
            int R    = rem >> 3;           // local s 0..127
            int dch  = rem & 7;            // 16B chunk along d
            s8v val = *(const s8v*)&SMEM[R * 128 +
                          (((hl * 8 + dch) ^ (R & 15)) << 3)];
            *(s8v*)(OF + (((size_t)bb * NH + h0 + hl) * SEQ + s0 + R) * 64
                       + dch * 8) = val;
        }
    } else {
        // ---- V: transpose via LDS [128 n][128 m], fp16 [B,H,D,S] ----
        #pragma unroll
        for (int mt = 0; mt < 4; mt++) {
            #pragma unroll
            for (int nt = 0; nt < 4; nt++) {
                int n = wc * 64 + nt * 16 + l15;
                float bv_ = bias[n0 + n];
                #pragma unroll
                for (int r = 0; r < 4; r++) {
                    int m = wr * 64 + mt * 16 + quad * 4 + r;
                    float v = acc[mt][nt][r] + bv_;
                    SMEM[n * 128 + (((m >> 3) ^ (n & 15)) << 3) + (m & 7)]
                        = f32_to_f16(v);
                }
            }
        }
        __syncthreads();
        // drain: per instruction a wave covers 4 full d-rows (4 x 256B)
        #pragma unroll
        for (int cc = 0; cc < 8; cc++) {
            int idx = cc * 256 + t;        // 0..2047
            int n   = idx >> 4;            // local col: h*64+d, 0..127
            int mc  = idx & 15;            // 16B chunk along s
            int d   = n & 63;
            int hh  = n >> 6;
            size_t obase = ((size_t)((bb * NH + h0 + hh) * HD + d)) * SEQ + s0;
            s8v val = *(const s8v*)&SMEM[n * 128 + ((mc ^ (n & 15)) << 3)];
            *(s8v*)(VtF + obase + mc * 8) = val;
        }
    }
}

// ---------------------------------------------------------------------------
// MFMA flash attention. Round-11: QBLK 64->128 — each wave owns TWO 16-row
// Q groups (g=0,1), so each K fragment read feeds 8 QK MFMA and each V
// fragment is read ONCE for both g's PV MFMA. LDS read:MFMA ratio 1:1 -> 1:2
// (total ds_read volume halves; R10 model: LDS reads ~50% of kernel time).
// Grid 512, 2 blocks/CU. Single SMEM array so the 16KB O-transpose epilogue
// aliases KS+VtS. Swapped QK^T + key-permuted staging + reg-P + raw exp2
// (R8/R10-verified) unchanged.
// ---------------------------------------------------------------------------
__global__ __launch_bounds__(256, 2)
void flash_attn(const u16* __restrict__ QF, const u16* __restrict__ KF,
                const u16* __restrict__ VtF,
                const float* __restrict__ kmax2,
                u16* __restrict__ AOF) {
    __shared__ __align__(16) u16 SM[9728];
    // KS[sub] @ sub*2304 (32 rows x 72), VtS[sub] @ 4608 + sub*2560 (64 x 40)
    #define KSp(sub) (SM + (sub) * 2304)
    #define VSp(sub) (SM + 4608 + (sub) * 2560)

    const int t    = threadIdx.x;
    const int w    = t >> 6;
    const int lane = t & 63;
    const int quad = lane >> 4;
    const int l15  = lane & 15;

    const int bid = blockIdx.x;
    const int xcd = bid & 7;
    const int j   = bid >> 3;          // 0..63
    const int bh  = xcd * 4 + (j & 3); // 0..31
    const int q0  = (j >> 2) * 128;    // 0..15 * 128

    const size_t kvbase = (size_t)bh * SEQ * HD;
    const float km2 = kmax2[0];
    const float C1 = 0.125f * 1.44269504089f;   // scale * log2(e)

    // ---- Q fragments for g=0,1; static softmax bounds (log2 domain) ----
    h8 qf[2][2];
    float mb2[2];
    #pragma unroll
    for (int g = 0; g < 2; g++) {
        const u16* qp = QF + kvbase +
            (size_t)(q0 + g * 64 + w * 16 + l15) * HD + quad * 8;
        qf[g][0] = *(const h8*)qp;
        qf[g][1] = *(const h8*)(qp + 32);
        float qn2 = 0.f;
        #pragma unroll
        for (int st = 0; st < 2; st++)
            #pragma unroll
            for (int e = 0; e < 8; e++) {
                float v = (float)qf[g][st][e];
                qn2 += v * v;
            }
        qn2 += __shfl_xor(qn2, 16, 64);
        qn2 += __shfl_xor(qn2, 32, 64);   // row norm^2, replicated over quads
        mb2[g] = sqrtf(qn2 * km2) * C1;
    }

    f4v o[2][4];
    float lsum[2];
    #pragma unroll
    for (int g = 0; g < 2; g++) {
        #pragma unroll
        for (int nt = 0; nt < 4; nt++) o[g][nt] = (f4v){0.f, 0.f, 0.f, 0.f};
        lsum[g] = 0.f;
    }

    // ---- staging addresses; K rows permuted: phys row krow holds key pkey ----
    const int krow = t >> 3;                 // physical LDS row 0..31
    const int kdc  = (t & 7) * 8;            // 16B chunk along d
    const int pkey = (krow & 3) + 8 * ((krow >> 2) & 3) + 4 * (krow >> 4);
    const u16* kgp = KF + kvbase + (size_t)pkey * HD + kdc;
    const int vd   = t >> 2;                 // 0..63
    const int vkc  = (t & 3) * 8;            // 16B chunk along keys
    const int vcol = vkc ^ (((vd >> 3) & 3) << 3);
    const u16* vgp = VtF + (size_t)bh * HD * SEQ + (size_t)vd * SEQ + vkc;

    // prologue: prefetch tile 0 into registers
    s8v krg0 = *(const s8v*)(kgp);
    s8v krg1 = *(const s8v*)(kgp + (size_t)32 * HD);
    s8v vrg0 = *(const s8v*)(vgp);
    s8v vrg1 = *(const s8v*)(vgp + 32);

    for (int k0 = 0; k0 < SEQ; k0 += 64) {
        __syncthreads();                     // prev compute's LDS reads done
        *(s8v*)&KSp(0)[krow * 72 + kdc] = krg0;
        *(s8v*)&KSp(1)[krow * 72 + kdc] = krg1;
        *(s8v*)&VSp(0)[vd * 40 + vcol]  = vrg0;
        *(s8v*)&VSp(1)[vd * 40 + vcol]  = vrg1;
        if (k0 + 64 < SEQ) {
            const u16* kn = kgp + (size_t)(k0 + 64) * HD;
            krg0 = *(const s8v*)(kn);
            krg1 = *(const s8v*)(kn + (size_t)32 * HD);
            vrg0 = *(const s8v*)(vgp + k0 + 64);
            vrg1 = *(const s8v*)(vgp + k0 + 96);
        }
        __syncthreads();

        #pragma unroll
        for (int sub = 0; sub < 2; sub++) {
            // phys rows l15 / 16+l15 = key groups {a+8b} / {a+8b+4}
            const u16* kb0 = KSp(sub) + l15 * 72 + quad * 8;
            const u16* kb1 = KSp(sub) + (16 + l15) * 72 + quad * 8;
            h8 kh0 = *(const h8*)kb0, kh1 = *(const h8*)(kb0 + 32);
            h8 kh2 = *(const h8*)kb1, kh3 = *(const h8*)(kb1 + 32);

            // S^T per g: lane(l15,quad) reg r = S[q=l15][key 8*quad+r (+4)]
            h8 pb[2];
            #pragma unroll
            for (int g = 0; g < 2; g++) {
                f4v sc0 = (f4v){0.f, 0.f, 0.f, 0.f};
                f4v sc1 = (f4v){0.f, 0.f, 0.f, 0.f};
                __builtin_amdgcn_s_setprio(1);
                sc0 = MFMAH(kh0, qf[g][0], sc0);
                sc0 = MFMAH(kh1, qf[g][1], sc0);
                sc1 = MFMAH(kh2, qf[g][0], sc1);
                sc1 = MFMAH(kh3, qf[g][1], sc1);
                __builtin_amdgcn_s_setprio(0);

                // in-register softmax (log2 domain, raw v_exp_f32)
                float p[8];
                #pragma unroll
                for (int r = 0; r < 4; r++) {
                    p[r]     = __builtin_amdgcn_exp2f(sc0[r] * C1 - mb2[g]);
                    p[4 + r] = __builtin_amdgcn_exp2f(sc1[r] * C1 - mb2[g]);
                }
                lsum[g] += ((p[0] + p[1]) + (p[2] + p[3]))
                         + ((p[4] + p[5]) + (p[6] + p[7]));

                __half2* pp = (__half2*)&pb[g];
                pp[0] = __floats2half2_rn(p[0], p[1]);
                pp[1] = __floats2half2_rn(p[2], p[3]);
                pp[2] = __floats2half2_rn(p[4], p[5]);
                pp[3] = __floats2half2_rn(p[6], p[7]);
            }

            // O^T += V^T·P^T — each V fragment read ONCE, used for both g
            __builtin_amdgcn_s_setprio(1);
            #pragma unroll
            for (int nt = 0; nt < 4; nt++) {
                int dim = nt * 16 + l15;
                int voff = dim * 40 + ((quad * 8) ^ (((dim >> 3) & 3) << 3));
                h8 vf = *(const h8*)&VSp(sub)[voff];
                o[0][nt] = MFMAH(vf, pb[0], o[0][nt]);
                o[1][nt] = MFMAH(vf, pb[1], o[1][nt]);
            }
            __builtin_amdgcn_s_setprio(0);
        }
    }

    // ---- epilogue: reduce l, normalize, LDS transpose (aliases SM), store ----
    float inv_l[2];
    #pragma unroll
    for (int g = 0; g < 2; g++) {
        float l = lsum[g];
        l += __shfl_xor(l, 16, 64);
        l += __shfl_xor(l, 32, 64);
        inv_l[g] = 1.0f / l;
    }

    const int b = bh >> 4;
    const int h = bh & 15;
    u16* OS = SM;                        // 128 x 64 u16 = 16 KB <= 19456 B
    __syncthreads();                     // all waves done reading KS/VtS
    #pragma unroll
    for (int g = 0; g < 2; g++) {
        const int srow = g * 64 + w * 16 + l15;   // local s 0..127
        #pragma unroll
        for (int nt = 0; nt < 4; nt++) {
            #pragma unroll
            for (int r = 0; r < 4; r++) {
                int d = nt * 16 + quad * 4 + r;
                OS[srow * 64 + (((d >> 3) ^ (srow & 7)) << 3) + (d & 7)]
                    = f32_to_f16(o[g][nt][r] * inv_l[g]);
            }
        }
    }
    __syncthreads();
    // per instruction: wave covers 8 full 128B lines of [B,S,H,D]
    #pragma unroll
    for (int cc = 0; cc < 4; cc++) {
        int idx = cc * 256 + t;          // 0..1023
        int sr  = idx >> 3;              // 0..127
        int dch = idx & 7;
        s8v val = *(const s8v*)&OS[sr * 64 + ((dch ^ (sr & 7)) << 3)];
        *(s8v*)(AOF + (((size_t)b * SEQ + q0 + sr) * NH + h) * HD + dch * 8)
            = val;
    }
    #undef KSp
    #undef VSp
}

// ---------------------------------------------------------------------------
// Out-projection fp16 MFMA GEMM — BM=128 BN=64 BK=64, grid 512 (unchanged).
// ---------------------------------------------------------------------------
__global__ __launch_bounds__(256, 2)
void gemm_out(const u16* __restrict__ AF, const u16* __restrict__ BF,
              const float* __restrict__ bias, float* __restrict__ out) {
    __shared__ __align__(16) u16 SMEM[24576];   // 48 KB

    const int t    = threadIdx.x;
    const int w    = t >> 6;
    const int lane = t & 63;
    const int quad = lane >> 4;
    const int l15  = lane & 15;
    const int wr   = w >> 1;        // m-half (64 rows)
    const int wc   = w & 1;         // n-half (32 cols)

    const int bid = blockIdx.x;
    const int xcd = bid & 7;
    const int j   = bid >> 3;              // 0..63
    const int m0  = (xcd * 4 + (j & 3)) * 128;
    const int n0  = (j >> 2) * 64;         // 0..15 * 64

    const int lr = lane >> 3;
    const int lc = (((lane & 7) ^ lr)) * 8;

    f4v acc[4][2];
    #pragma unroll
    for (int i = 0; i < 4; i++)
        #pragma unroll
        for (int jj = 0; jj < 2; jj++)
            acc[i][jj] = (f4v){0.f, 0.f, 0.f, 0.f};

#define STAGE(K0, DB) do {                                                   \
    u16* As_ = SMEM + (DB);                                                  \
    u16* Bs_ = As_ + 8192;                                                   \
    _Pragma("unroll")                                                        \
    for (int jj_ = 0; jj_ < 4; jj_++) {                                      \
        int seg = jj_ * 4 + w;                                               \
        gld16(AF + (size_t)(m0 + seg * 8 + lr) * KDIM + (K0) + lc,           \
              As_ + seg * 512);                                              \
    }                                                                        \
    _Pragma("unroll")                                                        \
    for (int jj_ = 0; jj_ < 2; jj_++) {                                      \
        int seg = jj_ * 4 + w;                                               \
        gld16(BF + (size_t)(n0 + seg * 8 + lr) * KDIM + (K0) + lc,           \
              Bs_ + seg * 512);                                              \
    }                                                                        \
} while (0)

    STAGE(0, 0);
    __syncthreads();

    int buf = 0;
    for (int k0 = 0; k0 < KDIM; k0 += 64) {
        if (k0 + 64 < KDIM) STAGE(k0 + 64, (buf ^ 1) * 12288);

        const u16* As = SMEM + buf * 12288;
        const u16* Bs = As + 8192;
        #pragma unroll
        for (int kk = 0; kk < 2; kk++) {
            const int swz = ((kk * 4 + quad) ^ (l15 & 7)) << 3;
            h8 a[4], b[2];
            #pragma unroll
            for (int mt = 0; mt < 4; mt++)
                a[mt] = *(const h8*)&As[(wr * 64 + mt * 16 + l15) * 64 + swz];
            #pragma unroll
            for (int nt = 0; nt < 2; nt++)
                b[nt] = *(const h8*)&Bs[(wc * 32 + nt * 16 + l15) * 64 + swz];
            #pragma unroll
            for (int mt = 0; mt < 4; mt++)
                #pragma unroll
                for (int nt = 0; nt < 2; nt++)
                    acc[mt][nt] = MFMAH(a[mt], b[nt], acc[mt][nt]);
        }
        __syncthreads();
        buf ^= 1;
    }
#undef STAGE

    #pragma unroll
    for (int mt = 0; mt < 4; mt++) {
        #pragma unroll
        for (int nt = 0; nt < 2; nt++) {
            int n = n0 + wc * 32 + nt * 16 + l15;
            float bv = bias[n];
            #pragma unroll
            for (int r = 0; r < 4; r++) {
                int m = m0 + wr * 64 + mt * 16 + quad * 4 + r;
                out[(size_t)m * 1024 + n] = acc[mt][nt][r] + bv;
            }
        }
    }
}

// ---------------------------------------------------------------------------
extern "C" void kernel_launch(void* const* d_in, const int* in_sizes, int n_in,
                              void* d_out, int out_size, void* d_ws, size_t ws_size,
                              hipStream_t stream) {
    const float* x  = (const float*)d_in[0];
    const float* Wq = (const float*)d_in[1];
    const float* bq = (const float*)d_in[2];
    const float* Wk = (const float*)d_in[3];
    const float* bk = (const float*)d_in[4];
    const float* Wv = (const float*)d_in[5];
    const float* bv = (const float*)d_in[6];
    const float* Wo = (const float*)d_in[7];
    const float* bo = (const float*)d_in[8];
    float* out = (float*)d_out;

    const size_t TEN = (size_t)MROWS * KDIM;     // 4,194,304
    const size_t WSZ = (size_t)KDIM * KDIM;      // 1,048,576

    u16* xF  = (u16*)d_ws;
    u16* WqF = xF + TEN;
    u16* WkF = WqF + WSZ;
    u16* WvF = WkF + WSZ;
    u16* WoF = WvF + WSZ;
    u16* QF  = WoF + WSZ;
    u16* KF  = QF + TEN;
    u16* VtF = KF + TEN;
    float* km2 = (float*)(VtF + TEN);
    float2* ropeT = (float2*)(km2 + 4);          // 2048*32 float2 = 512 KB
    u16* AOF = xF;          // x dead after qkv_gemm

    convert_f16<<<4352, 256, 0, stream>>>(x, Wq, Wk, Wv, Wo,
                                          xF, WqF, WkF, WvF, WoF, ropeT);

    hipMemsetAsync(km2, 0, 4, stream);

    qkv_gemm<<<768, 256, 0, stream>>>(xF, WqF, WkF, WvF,
                                      bq, bk, bv, ropeT, QF, KF, VtF, km2);

    flash_attn<<<512, 256, 0, stream>>>(QF, KF, VtF, km2, AOF);

    gemm_out<<<512, 256, 0, stream>>>(AOF, WoF, bo, out);
}

// Round 12
// 197.385 us; speedup vs baseline: 1.0779x; 1.0079x over previous
//
#include <hip/hip_runtime.h>
#include <hip/hip_fp16.h>
#include <math.h>

#define D_MODEL 1024
#define NH 16
#define HD 64
#define SEQ 2048
#define BATCH 2
#define MROWS (BATCH*SEQ)   // 4096
#define KDIM 1024

typedef unsigned short u16;
typedef __attribute__((ext_vector_type(8))) _Float16 h8;   // 8 f16 (4 VGPRs)
typedef __attribute__((ext_vector_type(8))) short s8v;
typedef __attribute__((ext_vector_type(4))) float f4v;

#define MFMAH(a, b, c) __builtin_amdgcn_mfma_f32_16x16x32_f16(a, b, c, 0, 0, 0)

// async global->LDS DMA, 16B/lane; LDS dest must be wave-uniform base
__device__ __forceinline__ void gld16(const u16* g, u16* l) {
    __builtin_amdgcn_global_load_lds(
        (const __attribute__((address_space(1))) void*)g,
        (__attribute__((address_space(3))) void*)l, 16, 0, 0);
}

__device__ __forceinline__ u16 f32_to_f16(float f) {
    return __half_as_ushort(__float2half(f));   // v_cvt_f16_f32, RNE
}

// ---------------------------------------------------------------------------
// fp32 -> fp16 conversion for x (4M) + 4 W (1M each), 8 elems/thread, PLUS
// RoPE cos/sin table build (blocks 4096..4351): ropeT[s*32+dd].
// ---------------------------------------------------------------------------
__global__ __launch_bounds__(256)
void convert_f16(const float* __restrict__ x,
                 const float* __restrict__ Wq, const float* __restrict__ Wk,
                 const float* __restrict__ Wv, const float* __restrict__ Wo,
                 u16* __restrict__ xF,
                 u16* __restrict__ WqF, u16* __restrict__ WkF,
                 u16* __restrict__ WvF, u16* __restrict__ WoF,
                 float2* __restrict__ ropeT) {
    int i = blockIdx.x * 256 + threadIdx.x;
    if (i >= (1 << 20)) {
        // ---- RoPE table: s in [0,2048), dd in [0,32) ----
        int idx2 = i - (1 << 20);          // 0..65535
        int s  = idx2 >> 5;
        int dd = idx2 & 31;
        float inv = __expf(-(float)dd * 0.2878231366f);   // 1e4^(-dd/32)
        float ang = (float)s * inv;
        ropeT[idx2] = make_float2(cosf(ang), sinf(ang));  // same math as before
        return;
    }
    const float* src;
    u16* dst;
    int idx;
    if (i < (1 << 19)) {
        src = x; dst = xF; idx = i;
    } else {
        int j = i - (1 << 19);
        int w = j >> 17;
        idx = j & ((1 << 17) - 1);
        switch (w) {
            case 0:  src = Wq; dst = WqF; break;
            case 1:  src = Wk; dst = WkF; break;
            case 2:  src = Wv; dst = WvF; break;
            default: src = Wo; dst = WoF; break;
        }
    }
    float4 a = ((const float4*)src)[idx * 2];
    float4 b = ((const float4*)src)[idx * 2 + 1];
    s8v o;
    o[0] = (short)f32_to_f16(a.x); o[1] = (short)f32_to_f16(a.y);
    o[2] = (short)f32_to_f16(a.z); o[3] = (short)f32_to_f16(a.w);
    o[4] = (short)f32_to_f16(b.x); o[5] = (short)f32_to_f16(b.y);
    o[6] = (short)f32_to_f16(b.z); o[7] = (short)f32_to_f16(b.w);
    ((s8v*)dst)[idx] = o;
}

// ---------------------------------------------------------------------------
// Fused QKV fp16 MFMA GEMM — BM=128 BN=128 BK=64, 64KB LDS dbuf,
// 2 blocks/CU. global_load_lds w=16, source-side XOR swizzle. Grid 768.
// Q,K: fused RoPE (table) -> LDS-staged full-line stores. K: atomicMax
// row-norm^2. V: LDS transpose -> fp16 [B,H,D,S].  (unchanged from R8)
// ---------------------------------------------------------------------------
__global__ __launch_bounds__(256, 2)
void qkv_gemm(const u16* __restrict__ xF, const u16* __restrict__ WqF,
              const u16* __restrict__ WkF, const u16* __restrict__ WvF,
              const float* __restrict__ bq, const float* __restrict__ bk,
              const float* __restrict__ bv,
              const float2* __restrict__ ropeT,
              u16* __restrict__ QF, u16* __restrict__ KF,
              u16* __restrict__ VtF, float* __restrict__ km2) {
    __shared__ __align__(16) u16 SMEM[32768];   // 64 KB

    const int t    = threadIdx.x;
    const int w    = t >> 6;
    const int lane = t & 63;
    const int quad = lane >> 4;
    const int l15  = lane & 15;
    const int wr   = w >> 1;
    const int wc   = w & 1;

    const int bid  = blockIdx.x;
    const int xcd  = bid & 7;
    const int j    = bid >> 3;          // 0..95
    const int m0   = (xcd * 4 + (j & 3)) * 128;
    const int yt   = j >> 2;            // 0..23
    const int wsel = yt >> 3;
    const int n0   = (yt & 7) * 128;

    const u16* Bg;
    const float* bias;
    if (wsel == 0)      { Bg = WqF; bias = bq; }
    else if (wsel == 1) { Bg = WkF; bias = bk; }
    else                { Bg = WvF; bias = bv; }

    const int lr = lane >> 3;                 // row within seg
    const int lc = (((lane & 7) ^ lr)) * 8;   // swizzled global u16 col

    f4v acc[4][4];
    #pragma unroll
    for (int i = 0; i < 4; i++)
        #pragma unroll
        for (int jj = 0; jj < 4; jj++)
            acc[i][jj] = (f4v){0.f, 0.f, 0.f, 0.f};

#define STAGE(K0, DB) do {                                                   \
    u16* As_ = SMEM + (DB);                                                  \
    u16* Bs_ = As_ + 8192;                                                   \
    _Pragma("unroll")                                                        \
    for (int jj_ = 0; jj_ < 4; jj_++) {                                      \
        int seg = jj_ * 4 + w;                                               \
        gld16(xF + (size_t)(m0 + seg * 8 + lr) * KDIM + (K0) + lc,           \
              As_ + seg * 512);                                              \
        gld16(Bg + (size_t)(n0 + seg * 8 + lr) * KDIM + (K0) + lc,           \
              Bs_ + seg * 512);                                              \
    }                                                                        \
} while (0)

    STAGE(0, 0);
    __syncthreads();

    int buf = 0;
    for (int k0 = 0; k0 < KDIM; k0 += 64) {
        if (k0 + 64 < KDIM) STAGE(k0 + 64, (buf ^ 1) * 16384);

        const u16* As = SMEM + buf * 16384;
        const u16* Bs = As + 8192;
        #pragma unroll
        for (int kk = 0; kk < 2; kk++) {
            const int swz = ((kk * 4 + quad) ^ (l15 & 7)) << 3;
            h8 a[4], b[4];
            #pragma unroll
            for (int mt = 0; mt < 4; mt++)
                a[mt] = *(const h8*)&As[(wr * 64 + mt * 16 + l15) * 64 + swz];
            #pragma unroll
            for (int nt = 0; nt < 4; nt++)
                b[nt] = *(const h8*)&Bs[(wc * 64 + nt * 16 + l15) * 64 + swz];
            #pragma unroll
            for (int mt = 0; mt < 4; mt++)
                #pragma unroll
                for (int nt = 0; nt < 4; nt++)
                    acc[mt][nt] = MFMAH(a[mt], b[nt], acc[mt][nt]);
        }
        __syncthreads();
        buf ^= 1;
    }
#undef STAGE

    const int bb = m0 >> 11;
    const int s0 = m0 & 2047;
    const int h0 = n0 >> 6;             // first of 2 heads in this n-tile

    if (wsel < 2) {
        // ---- Q/K: fused RoPE (table) -> LDS tile [128 s][128 n] swizzled ----
        u16* OF = (wsel == 0) ? QF : KF;
        float kn_max = 0.f;
        #pragma unroll
        for (int mt = 0; mt < 4; mt++) {
            #pragma unroll
            for (int r = 0; r < 4; r++) {
                int R = wr * 64 + mt * 16 + quad * 4 + r;     // local s
                int s = s0 + R;
                float rowsum = 0.f;
                #pragma unroll
                for (int nt = 0; nt < 2; nt++) {
                    int col = wc * 64 + nt * 16 + l15;        // local n
                    int n1 = n0 + col;
                    int dd = n1 & 31;
                    float v1 = acc[mt][nt][r]     + bias[n1];
                    float v2 = acc[mt][nt + 2][r] + bias[n1 + 32];
                    float2 cssn = ropeT[(s << 5) | dd];       // coalesced
                    float cs  = cssn.x;
                    float sn  = cssn.y;
                    float r1 = v1 * cs - v2 * sn;
                    float r2 = v2 * cs + v1 * sn;
                    rowsum += v1 * v1 + v2 * v2;     // norm is RoPE-invariant
                    SMEM[R * 128 + (((col >> 3) ^ (R & 15)) << 3) + (col & 7)]
                        = f32_to_f16(r1);
                    int col2 = col + 32;
                    SMEM[R * 128 + (((col2 >> 3) ^ (R & 15)) << 3) + (col2 & 7)]
                        = f32_to_f16(r2);
                }
                if (wsel == 1) {
                    rowsum += __shfl_xor(rowsum, 1, 64);
                    rowsum += __shfl_xor(rowsum, 2, 64);
                    rowsum += __shfl_xor(rowsum, 4, 64);
                    rowsum += __shfl_xor(rowsum, 8, 64);
                    kn_max = fmaxf(kn_max, rowsum);
                }
            }
        }
        if (wsel == 1) {
            kn_max = fmaxf(kn_max, __shfl_xor(kn_max, 16, 64));
            kn_max = fmaxf(kn_max, __shfl_xor(kn_max, 32, 64));
            if (lane == 0) atomicMax((int*)km2, __float_as_int(kn_max));
        }
        __syncthreads();
        // drain: per instruction each wave writes 1 KB contiguous [B,H,S,D]
        #pragma unroll
        for (int cc = 0; cc < 8; cc++) {
            int idx  = cc * 256 + t;       // 0..2047
            int hl   = idx >> 10;          // 0..1
            int rem  = idx & 1023;
            int R    = rem >> 3;           // local s 0..127
            int dch  = rem & 7;            // 16B chunk along d
            s8v val = *(const s8v*)&SMEM[R * 128 +
                          (((hl * 8 + dch) ^ (R & 15)) << 3)];
            *(s8v*)(OF + (((size_t)bb * NH + h0 + hl) * SEQ + s0 + R) * 64
                       + dch * 8) = val;
        }
    } else {
        // ---- V: transpose via LDS [128 n][128 m], fp16 [B,H,D,S] ----
        #pragma unroll
        for (int mt = 0; mt < 4; mt++) {
            #pragma unroll
            for (int nt = 0; nt < 4; nt++) {
                int n = wc * 64 + nt * 16 + l15;
                float bv_ = bias[n0 + n];
                #pragma unroll
                for (int r = 0; r < 4; r++) {
                    int m = wr * 64 + mt * 16 + quad * 4 + r;
                    float v = acc[mt][nt][r] + bv_;
                    SMEM[n * 128 + (((m >> 3) ^ (n & 15)) << 3) + (m & 7)]
                        = f32_to_f16(v);
                }
            }
        }
        __syncthreads();
        // drain: per instruction a wave covers 4 full d-rows (4 x 256B)
        #pragma unroll
        for (int cc = 0; cc < 8; cc++) {
            int idx = cc * 256 + t;        // 0..2047
            int n   = idx >> 4;            // local col: h*64+d, 0..127
            int mc  = idx & 15;            // 16B chunk along s
            int d   = n & 63;
            int hh  = n >> 6;
            size_t obase = ((size_t)((bb * NH + h0 + hh) * HD + d)) * SEQ + s0;
            s8v val = *(const s8v*)&SMEM[n * 128 + ((mc ^ (n & 15)) << 3)];
            *(s8v*)(VtF + obase + mc * 8) = val;
        }
    }
}

// ---------------------------------------------------------------------------
// MFMA flash attention. Round-12: DOUBLE-BUFFERED K/V LDS (38.9KB, still
// 2 blocks/CU) -> ONE barrier per iteration (was 2): iter t writes tile t+1
// into buf^1 while computing tile t from buf; the single barrier separates
// buf^1-writes(t) from buf^1-reads(t+1) AND buf-reads(t) from buf-writes(t+1).
// ds_writes now overlap compute. QBLK=128 (g=2 reuse), swapped QK^T,
// key-permuted staging, reg-P, raw exp2 — all R11-verified, unchanged.
// ---------------------------------------------------------------------------
__global__ __launch_bounds__(256, 2)
void flash_attn(const u16* __restrict__ QF, const u16* __restrict__ KF,
                const u16* __restrict__ VtF,
                const float* __restrict__ kmax2,
                u16* __restrict__ AOF) {
    __shared__ __align__(16) u16 SM[19456];   // 2 x 9728 (dbuf)
    // within buf b: KS[sub] @ b*9728 + sub*2304, VtS[sub] @ b*9728+4608+sub*2560
    #define KSp(b, sub) (SM + (b) * 9728 + (sub) * 2304)
    #define VSp(b, sub) (SM + (b) * 9728 + 4608 + (sub) * 2560)

    const int t    = threadIdx.x;
    const int w    = t >> 6;
    const int lane = t & 63;
    const int quad = lane >> 4;
    const int l15  = lane & 15;

    const int bid = blockIdx.x;
    const int xcd = bid & 7;
    const int j   = bid >> 3;          // 0..63
    const int bh  = xcd * 4 + (j & 3); // 0..31
    const int q0  = (j >> 2) * 128;    // 0..15 * 128

    const size_t kvbase = (size_t)bh * SEQ * HD;
    const float km2 = kmax2[0];
    const float C1 = 0.125f * 1.44269504089f;   // scale * log2(e)

    // ---- Q fragments for g=0,1; static softmax bounds (log2 domain) ----
    h8 qf[2][2];
    float mb2[2];
    #pragma unroll
    for (int g = 0; g < 2; g++) {
        const u16* qp = QF + kvbase +
            (size_t)(q0 + g * 64 + w * 16 + l15) * HD + quad * 8;
        qf[g][0] = *(const h8*)qp;
        qf[g][1] = *(const h8*)(qp + 32);
        float qn2 = 0.f;
        #pragma unroll
        for (int st = 0; st < 2; st++)
            #pragma unroll
            for (int e = 0; e < 8; e++) {
                float v = (float)qf[g][st][e];
                qn2 += v * v;
            }
        qn2 += __shfl_xor(qn2, 16, 64);
        qn2 += __shfl_xor(qn2, 32, 64);   // row norm^2, replicated over quads
        mb2[g] = sqrtf(qn2 * km2) * C1;
    }

    f4v o[2][4];
    float lsum[2];
    #pragma unroll
    for (int g = 0; g < 2; g++) {
        #pragma unroll
        for (int nt = 0; nt < 4; nt++) o[g][nt] = (f4v){0.f, 0.f, 0.f, 0.f};
        lsum[g] = 0.f;
    }

    // ---- staging addresses; K rows permuted: phys row krow holds key pkey ----
    const int krow = t >> 3;                 // physical LDS row 0..31
    const int kdc  = (t & 7) * 8;            // 16B chunk along d
    const int pkey = (krow & 3) + 8 * ((krow >> 2) & 3) + 4 * (krow >> 4);
    const u16* kgp = KF + kvbase + (size_t)pkey * HD + kdc;
    const int vd   = t >> 2;                 // 0..63
    const int vkc  = (t & 3) * 8;            // 16B chunk along keys
    const int vcol = vkc ^ (((vd >> 3) & 3) << 3);
    const u16* vgp = VtF + (size_t)bh * HD * SEQ + (size_t)vd * SEQ + vkc;

    // prologue: tile 0 -> regs -> buf0; tile 1 -> regs; one barrier
    s8v krg0 = *(const s8v*)(kgp);
    s8v krg1 = *(const s8v*)(kgp + (size_t)32 * HD);
    s8v vrg0 = *(const s8v*)(vgp);
    s8v vrg1 = *(const s8v*)(vgp + 32);
    *(s8v*)&KSp(0, 0)[krow * 72 + kdc] = krg0;
    *(s8v*)&KSp(0, 1)[krow * 72 + kdc] = krg1;
    *(s8v*)&VSp(0, 0)[vd * 40 + vcol]  = vrg0;
    *(s8v*)&VSp(0, 1)[vd * 40 + vcol]  = vrg1;
    {
        const u16* kn = kgp + (size_t)64 * HD;
        krg0 = *(const s8v*)(kn);
        krg1 = *(const s8v*)(kn + (size_t)32 * HD);
        vrg0 = *(const s8v*)(vgp + 64);
        vrg1 = *(const s8v*)(vgp + 96);
    }
    __syncthreads();

    int cur = 0;
    for (int k0 = 0; k0 < SEQ; k0 += 64) {
        // ---- write tile t+1 (in regs) into buf^1; overlaps compute below ----
        *(s8v*)&KSp(cur ^ 1, 0)[krow * 72 + kdc] = krg0;
        *(s8v*)&KSp(cur ^ 1, 1)[krow * 72 + kdc] = krg1;
        *(s8v*)&VSp(cur ^ 1, 0)[vd * 40 + vcol]  = vrg0;
        *(s8v*)&VSp(cur ^ 1, 1)[vd * 40 + vcol]  = vrg1;
        // ---- issue loads for tile t+2 ----
        if (k0 + 128 < SEQ) {
            const u16* kn = kgp + (size_t)(k0 + 128) * HD;
            krg0 = *(const s8v*)(kn);
            krg1 = *(const s8v*)(kn + (size_t)32 * HD);
            vrg0 = *(const s8v*)(vgp + k0 + 128);
            vrg1 = *(const s8v*)(vgp + k0 + 160);
        }

        // ---- compute tile t from buf[cur] ----
        #pragma unroll
        for (int sub = 0; sub < 2; sub++) {
            // phys rows l15 / 16+l15 = key groups {a+8b} / {a+8b+4}
            const u16* kb0 = KSp(cur, sub) + l15 * 72 + quad * 8;
            const u16* kb1 = KSp(cur, sub) + (16 + l15) * 72 + quad * 8;
            h8 kh0 = *(const h8*)kb0, kh1 = *(const h8*)(kb0 + 32);
            h8 kh2 = *(const h8*)kb1, kh3 = *(const h8*)(kb1 + 32);

            // S^T per g: lane(l15,quad) reg r = S[q=l15][key 8*quad+r (+4)]
            h8 pb[2];
            #pragma unroll
            for (int g = 0; g < 2; g++) {
                f4v sc0 = (f4v){0.f, 0.f, 0.f, 0.f};
                f4v sc1 = (f4v){0.f, 0.f, 0.f, 0.f};
                __builtin_amdgcn_s_setprio(1);
                sc0 = MFMAH(kh0, qf[g][0], sc0);
                sc0 = MFMAH(kh1, qf[g][1], sc0);
                sc1 = MFMAH(kh2, qf[g][0], sc1);
                sc1 = MFMAH(kh3, qf[g][1], sc1);
                __builtin_amdgcn_s_setprio(0);

                // in-register softmax (log2 domain, raw v_exp_f32)
                float p[8];
                #pragma unroll
                for (int r = 0; r < 4; r++) {
                    p[r]     = __builtin_amdgcn_exp2f(sc0[r] * C1 - mb2[g]);
                    p[4 + r] = __builtin_amdgcn_exp2f(sc1[r] * C1 - mb2[g]);
                }
                lsum[g] += ((p[0] + p[1]) + (p[2] + p[3]))
                         + ((p[4] + p[5]) + (p[6] + p[7]));

                __half2* pp = (__half2*)&pb[g];
                pp[0] = __floats2half2_rn(p[0], p[1]);
                pp[1] = __floats2half2_rn(p[2], p[3]);
                pp[2] = __floats2half2_rn(p[4], p[5]);
                pp[3] = __floats2half2_rn(p[6], p[7]);
            }

            // O^T += V^T·P^T — each V fragment read ONCE, used for both g
            __builtin_amdgcn_s_setprio(1);
            #pragma unroll
            for (int nt = 0; nt < 4; nt++) {
                int dim = nt * 16 + l15;
                int voff = dim * 40 + ((quad * 8) ^ (((dim >> 3) & 3) << 3));
                h8 vf = *(const h8*)&VSp(cur, sub)[voff];
                o[0][nt] = MFMAH(vf, pb[0], o[0][nt]);
                o[1][nt] = MFMAH(vf, pb[1], o[1][nt]);
            }
            __builtin_amdgcn_s_setprio(0);
        }

        __syncthreads();                 // single barrier per iteration
        cur ^= 1;
    }

    // ---- epilogue: reduce l, normalize, LDS transpose (aliases SM), store ----
    float inv_l[2];
    #pragma unroll
    for (int g = 0; g < 2; g++) {
        float l = lsum[g];
        l += __shfl_xor(l, 16, 64);
        l += __shfl_xor(l, 32, 64);
        inv_l[g] = 1.0f / l;
    }

    const int b = bh >> 4;
    const int h = bh & 15;
    u16* OS = SM;                        // 128 x 64 u16 = 16 KB <= 38912 B
    #pragma unroll
    for (int g = 0; g < 2; g++) {
        const int srow = g * 64 + w * 16 + l15;   // local s 0..127
        #pragma unroll
        for (int nt = 0; nt < 4; nt++) {
            #pragma unroll
            for (int r = 0; r < 4; r++) {
                int d = nt * 16 + quad * 4 + r;
                OS[srow * 64 + (((d >> 3) ^ (srow & 7)) << 3) + (d & 7)]
                    = f32_to_f16(o[g][nt][r] * inv_l[g]);
            }
        }
    }
    __syncthreads();
    // per instruction: wave covers 8 full 128B lines of [B,S,H,D]
    #pragma unroll
    for (int cc = 0; cc < 4; cc++) {
        int idx = cc * 256 + t;          // 0..1023
        int sr  = idx >> 3;              // 0..127
        int dch = idx & 7;
        s8v val = *(const s8v*)&OS[sr * 64 + ((dch ^ (sr & 7)) << 3)];
        *(s8v*)(AOF + (((size_t)b * SEQ + q0 + sr) * NH + h) * HD + dch * 8)
            = val;
    }
    #undef KSp
    #undef VSp
}

// ---------------------------------------------------------------------------
// Out-projection fp16 MFMA GEMM — BM=128 BN=64 BK=64, grid 512 (unchanged).
// ---------------------------------------------------------------------------
__global__ __launch_bounds__(256, 2)
void gemm_out(const u16* __restrict__ AF, const u16* __restrict__ BF,
              const float* __restrict__ bias, float* __restrict__ out) {
    __shared__ __align__(16) u16 SMEM[24576];   // 48 KB

    const int t    = threadIdx.x;
    const int w    = t >> 6;
    const int lane = t & 63;
    const int quad = lane >> 4;
    const int l15  = lane & 15;
    const int wr   = w >> 1;        // m-half (64 rows)
    const int wc   = w & 1;         // n-half (32 cols)

    const int bid = blockIdx.x;
    const int xcd = bid & 7;
    const int j   = bid >> 3;              // 0..63
    const int m0  = (xcd * 4 + (j & 3)) * 128;
    const int n0  = (j >> 2) * 64;         // 0..15 * 64

    const int lr = lane >> 3;
    const int lc = (((lane & 7) ^ lr)) * 8;

    f4v acc[4][2];
    #pragma unroll
    for (int i = 0; i < 4; i++)
        #pragma unroll
        for (int jj = 0; jj < 2; jj++)
            acc[i][jj] = (f4v){0.f, 0.f, 0.f, 0.f};

#define STAGE(K0, DB) do {                                                   \
    u16* As_ = SMEM + (DB);                                                  \
    u16* Bs_ = As_ + 8192;                                                   \
    _Pragma("unroll")                                                        \
    for (int jj_ = 0; jj_ < 4; jj_++) {                                      \
        int seg = jj_ * 4 + w;                                               \
        gld16(AF + (size_t)(m0 + seg * 8 + lr) * KDIM + (K0) + lc,           \
              As_ + seg * 512);                                              \
    }                                                                        \
    _Pragma("unroll")                                                        \
    for (int jj_ = 0; jj_ < 2; jj_++) {                                      \
        int seg = jj_ * 4 + w;                                               \
        gld16(BF + (size_t)(n0 + seg * 8 + lr) * KDIM + (K0) + lc,           \
              Bs_ + seg * 512);                                              \
    }                                                                        \
} while (0)

    STAGE(0, 0);
    __syncthreads();

    int buf = 0;
    for (int k0 = 0; k0 < KDIM; k0 += 64) {
        if (k0 + 64 < KDIM) STAGE(k0 + 64, (buf ^ 1) * 12288);

        const u16* As = SMEM + buf * 12288;
        const u16* Bs = As + 8192;
        #pragma unroll
        for (int kk = 0; kk < 2; kk++) {
            const int swz = ((kk * 4 + quad) ^ (l15 & 7)) << 3;
            h8 a[4], b[2];
            #pragma unroll
            for (int mt = 0; mt < 4; mt++)
                a[mt] = *(const h8*)&As[(wr * 64 + mt * 16 + l15) * 64 + swz];
            #pragma unroll
            for (int nt = 0; nt < 2; nt++)
                b[nt] = *(const h8*)&Bs[(wc * 32 + nt * 16 + l15) * 64 + swz];
            #pragma unroll
            for (int mt = 0; mt < 4; mt++)
                #pragma unroll
                for (int nt = 0; nt < 2; nt++)
                    acc[mt][nt] = MFMAH(a[mt], b[nt], acc[mt][nt]);
        }
        __syncthreads();
        buf ^= 1;
    }
#undef STAGE

    #pragma unroll
    for (int mt = 0; mt < 4; mt++) {
        #pragma unroll
        for (int nt = 0; nt < 2; nt++) {
            int n = n0 + wc * 32 + nt * 16 + l15;
            float bv = bias[n];
            #pragma unroll
            for (int r = 0; r < 4; r++) {
                int m = m0 + wr * 64 + mt * 16 + quad * 4 + r;
                out[(size_t)m * 1024 + n] = acc[mt][nt][r] + bv;
            }
        }
    }
}

// ---------------------------------------------------------------------------
extern "C" void kernel_launch(void* const* d_in, const int* in_sizes, int n_in,
                              void* d_out, int out_size, void* d_ws, size_t ws_size,
                              hipStream_t stream) {
    const float* x  = (const float*)d_in[0];
    const float* Wq = (const float*)d_in[1];
    const float* bq = (const float*)d_in[2];
    const float* Wk = (const float*)d_in[3];
    const float* bk = (const float*)d_in[4];
    const float* Wv = (const float*)d_in[5];
    const float* bv = (const float*)d_in[6];
    const float* Wo = (const float*)d_in[7];
    const float* bo = (const float*)d_in[8];
    float* out = (float*)d_out;

    const size_t TEN = (size_t)MROWS * KDIM;     // 4,194,304
    const size_t WSZ = (size_t)KDIM * KDIM;      // 1,048,576

    u16* xF  = (u16*)d_ws;
    u16* WqF = xF + TEN;
    u16* WkF = WqF + WSZ;
    u16* WvF = WkF + WSZ;
    u16* WoF = WvF + WSZ;
    u16* QF  = WoF + WSZ;
    u16* KF  = QF + TEN;
    u16* VtF = KF + TEN;
    float* km2 = (float*)(VtF + TEN);
    float2* ropeT = (float2*)(km2 + 4);          // 2048*32 float2 = 512 KB
    u16* AOF = xF;          // x dead after qkv_gemm

    convert_f16<<<4352, 256, 0, stream>>>(x, Wq, Wk, Wv, Wo,
                                          xF, WqF, WkF, WvF, WoF, ropeT);

    hipMemsetAsync(km2, 0, 4, stream);

    qkv_gemm<<<768, 256, 0, stream>>>(xF, WqF, WkF, WvF,
                                      bq, bk, bv, ropeT, QF, KF, VtF, km2);

    flash_attn<<<512, 256, 0, stream>>>(QF, KF, VtF, km2, AOF);

    gemm_out<<<512, 256, 0, stream>>>(AOF, WoF, bo, out);
}

// Round 13
// 193.415 us; speedup vs baseline: 1.1000x; 1.0205x over previous
//
#include <hip/hip_runtime.h>
#include <hip/hip_fp16.h>
#include <math.h>

#define D_MODEL 1024
#define NH 16
#define HD 64
#define SEQ 2048
#define BATCH 2
#define MROWS (BATCH*SEQ)   // 4096
#define KDIM 1024

typedef unsigned short u16;
typedef __attribute__((ext_vector_type(8))) _Float16 h8;   // 8 f16 (4 VGPRs)
typedef __attribute__((ext_vector_type(8))) short s8v;
typedef __attribute__((ext_vector_type(4))) float f4v;

#define MFMAH(a, b, c) __builtin_amdgcn_mfma_f32_16x16x32_f16(a, b, c, 0, 0, 0)

// async global->LDS DMA, 16B/lane; LDS dest must be wave-uniform base
__device__ __forceinline__ void gld16(const u16* g, u16* l) {
    __builtin_amdgcn_global_load_lds(
        (const __attribute__((address_space(1))) void*)g,
        (__attribute__((address_space(3))) void*)l, 16, 0, 0);
}

__device__ __forceinline__ u16 f32_to_f16(float f) {
    return __half_as_ushort(__float2half(f));   // v_cvt_f16_f32, RNE
}

// ---------------------------------------------------------------------------
// fp32 -> fp16 conversion for x (4M) + 4 W (1M each), 8 elems/thread, PLUS
// RoPE cos/sin table build (blocks 4096..4351): ropeT[s*32+dd].
// ---------------------------------------------------------------------------
__global__ __launch_bounds__(256)
void convert_f16(const float* __restrict__ x,
                 const float* __restrict__ Wq, const float* __restrict__ Wk,
                 const float* __restrict__ Wv, const float* __restrict__ Wo,
                 u16* __restrict__ xF,
                 u16* __restrict__ WqF, u16* __restrict__ WkF,
                 u16* __restrict__ WvF, u16* __restrict__ WoF,
                 float2* __restrict__ ropeT) {
    int i = blockIdx.x * 256 + threadIdx.x;
    if (i >= (1 << 20)) {
        // ---- RoPE table: s in [0,2048), dd in [0,32) ----
        int idx2 = i - (1 << 20);          // 0..65535
        int s  = idx2 >> 5;
        int dd = idx2 & 31;
        float inv = __expf(-(float)dd * 0.2878231366f);   // 1e4^(-dd/32)
        float ang = (float)s * inv;
        ropeT[idx2] = make_float2(cosf(ang), sinf(ang));  // same math as before
        return;
    }
    const float* src;
    u16* dst;
    int idx;
    if (i < (1 << 19)) {
        src = x; dst = xF; idx = i;
    } else {
        int j = i - (1 << 19);
        int w = j >> 17;
        idx = j & ((1 << 17) - 1);
        switch (w) {
            case 0:  src = Wq; dst = WqF; break;
            case 1:  src = Wk; dst = WkF; break;
            case 2:  src = Wv; dst = WvF; break;
            default: src = Wo; dst = WoF; break;
        }
    }
    float4 a = ((const float4*)src)[idx * 2];
    float4 b = ((const float4*)src)[idx * 2 + 1];
    s8v o;
    o[0] = (short)f32_to_f16(a.x); o[1] = (short)f32_to_f16(a.y);
    o[2] = (short)f32_to_f16(a.z); o[3] = (short)f32_to_f16(a.w);
    o[4] = (short)f32_to_f16(b.x); o[5] = (short)f32_to_f16(b.y);
    o[6] = (short)f32_to_f16(b.z); o[7] = (short)f32_to_f16(b.w);
    ((s8v*)dst)[idx] = o;
}

// ---------------------------------------------------------------------------
// Fused QKV fp16 MFMA GEMM — Round-13: BK=32, m97 [128][32] linear LDS,
// 32KB dbuf, __launch_bounds__(256,3) -> grid 768 = EXACTLY 3 blocks/CU,
// zero tail (R6-R12 config was 2/CU + a 256-block tail round at half
// utilization). global_load_lds w=16 staging (R2/R3-verified structure).
// Q,K: fused RoPE (table) -> LDS-staged full-line stores. K: atomicMax
// row-norm^2. V: LDS transpose -> fp16 [B,H,D,S].  (R6-verified epilogue)
// ---------------------------------------------------------------------------
__global__ __launch_bounds__(256, 3)
void qkv_gemm(const u16* __restrict__ xF, const u16* __restrict__ WqF,
              const u16* __restrict__ WkF, const u16* __restrict__ WvF,
              const float* __restrict__ bq, const float* __restrict__ bk,
              const float* __restrict__ bv,
              const float2* __restrict__ ropeT,
              u16* __restrict__ QF, u16* __restrict__ KF,
              u16* __restrict__ VtF, float* __restrict__ km2) {
    __shared__ __align__(16) u16 SMEM[16384];   // 32 KB
    // buf b: A [128][32] @ b*8192, B [128][32] @ b*8192+4096 (u16 units)

    const int t    = threadIdx.x;
    const int w    = t >> 6;
    const int lane = t & 63;
    const int quad = lane >> 4;
    const int l15  = lane & 15;
    const int wr   = w >> 1;
    const int wc   = w & 1;

    const int bid  = blockIdx.x;
    const int xcd  = bid & 7;
    const int j    = bid >> 3;          // 0..95
    const int m0   = (xcd * 4 + (j & 3)) * 128;
    const int yt   = j >> 2;            // 0..23
    const int wsel = yt >> 3;
    const int n0   = (yt & 7) * 128;

    const u16* Bg;
    const float* bias;
    if (wsel == 0)      { Bg = WqF; bias = bq; }
    else if (wsel == 1) { Bg = WkF; bias = bk; }
    else                { Bg = WvF; bias = bv; }

    // staging (m97/R2): seg = 16 rows x 32 cols = 1KB; lane -> row lane>>2,
    // 16B chunk (lane&3); wave w covers segs {2w, 2w+1} for A and B
    const int srA = lane >> 2;          // 0..15 row within seg
    const int scA = (lane & 3) * 8;     // u16 col

    f4v acc[4][4];
    #pragma unroll
    for (int i = 0; i < 4; i++)
        #pragma unroll
        for (int jj = 0; jj < 4; jj++)
            acc[i][jj] = (f4v){0.f, 0.f, 0.f, 0.f};

#define STAGE(K0, DB) do {                                                   \
    u16* As_ = SMEM + (DB);                                                  \
    u16* Bs_ = As_ + 4096;                                                   \
    _Pragma("unroll")                                                        \
    for (int jj_ = 0; jj_ < 2; jj_++) {                                      \
        int seg = w * 2 + jj_;                                               \
        int row = seg * 16 + srA;                                            \
        gld16(xF + (size_t)(m0 + row) * KDIM + (K0) + scA,                   \
              As_ + seg * 512);                                              \
        gld16(Bg + (size_t)(n0 + row) * KDIM + (K0) + scA,                   \
              Bs_ + seg * 512);                                              \
    }                                                                        \
} while (0)

    STAGE(0, 0);
    __syncthreads();

    int buf = 0;
    for (int k0 = 0; k0 < KDIM; k0 += 32) {
        if (k0 + 32 < KDIM) STAGE(k0 + 32, (buf ^ 1) * 8192);

        const u16* As = SMEM + buf * 8192;
        const u16* Bs = As + 4096;
        h8 a[4], b[4];
        #pragma unroll
        for (int i = 0; i < 4; i++) {
            a[i] = *(const h8*)&As[(wr * 64 + i * 16 + l15) * 32 + quad * 8];
            b[i] = *(const h8*)&Bs[(wc * 64 + i * 16 + l15) * 32 + quad * 8];
        }
        #pragma unroll
        for (int mt = 0; mt < 4; mt++)
            #pragma unroll
            for (int nt = 0; nt < 4; nt++)
                acc[mt][nt] = MFMAH(a[mt], b[nt], acc[mt][nt]);

        __syncthreads();                // drains vmcnt+lgkm; next buf ready
        buf ^= 1;
    }
#undef STAGE

    const int bb = m0 >> 11;
    const int s0 = m0 & 2047;
    const int h0 = n0 >> 6;             // first of 2 heads in this n-tile

    if (wsel < 2) {
        // ---- Q/K: fused RoPE (table) -> LDS tile [128 s][128 n] swizzled ----
        u16* OF = (wsel == 0) ? QF : KF;
        float kn_max = 0.f;
        #pragma unroll
        for (int mt = 0; mt < 4; mt++) {
            #pragma unroll
            for (int r = 0; r < 4; r++) {
                int R = wr * 64 + mt * 16 + quad * 4 + r;     // local s
                int s = s0 + R;
                float rowsum = 0.f;
                #pragma unroll
                for (int nt = 0; nt < 2; nt++) {
                    int col = wc * 64 + nt * 16 + l15;        // local n
                    int n1 = n0 + col;
                    int dd = n1 & 31;
                    float v1 = acc[mt][nt][r]     + bias[n1];
                    float v2 = acc[mt][nt + 2][r] + bias[n1 + 32];
                    float2 cssn = ropeT[(s << 5) | dd];       // coalesced
                    float cs  = cssn.x;
                    float sn  = cssn.y;
                    float r1 = v1 * cs - v2 * sn;
                    float r2 = v2 * cs + v1 * sn;
                    rowsum += v1 * v1 + v2 * v2;     // norm is RoPE-invariant
                    SMEM[R * 128 + (((col >> 3) ^ (R & 15)) << 3) + (col & 7)]
                        = f32_to_f16(r1);
                    int col2 = col + 32;
                    SMEM[R * 128 + (((col2 >> 3) ^ (R & 15)) << 3) + (col2 & 7)]
                        = f32_to_f16(r2);
                }
                if (wsel == 1) {
                    rowsum += __shfl_xor(rowsum, 1, 64);
                    rowsum += __shfl_xor(rowsum, 2, 64);
                    rowsum += __shfl_xor(rowsum, 4, 64);
                    rowsum += __shfl_xor(rowsum, 8, 64);
                    kn_max = fmaxf(kn_max, rowsum);
                }
            }
        }
        if (wsel == 1) {
            kn_max = fmaxf(kn_max, __shfl_xor(kn_max, 16, 64));
            kn_max = fmaxf(kn_max, __shfl_xor(kn_max, 32, 64));
            if (lane == 0) atomicMax((int*)km2, __float_as_int(kn_max));
        }
        __syncthreads();
        // drain: per instruction each wave writes 1 KB contiguous [B,H,S,D]
        #pragma unroll
        for (int cc = 0; cc < 8; cc++) {
            int idx  = cc * 256 + t;       // 0..2047
            int hl   = idx >> 10;          // 0..1
            int rem  = idx & 1023;
            int R    = rem >> 3;           // local s 0..127
            int dch  = rem & 7;            // 16B chunk along d
            s8v val = *(const s8v*)&SMEM[R * 128 +
                          (((hl * 8 + dch) ^ (R & 15)) << 3)];
            *(s8v*)(OF + (((size_t)bb * NH + h0 + hl) * SEQ + s0 + R) * 64
                       + dch * 8) = val;
        }
    } else {
        // ---- V: transpose via LDS [128 n][128 m], fp16 [B,H,D,S] ----
        #pragma unroll
        for (int mt = 0; mt < 4; mt++) {
            #pragma unroll
            for (int nt = 0; nt < 4; nt++) {
                int n = wc * 64 + nt * 16 + l15;
                float bv_ = bias[n0 + n];
                #pragma unroll
                for (int r = 0; r < 4; r++) {
                    int m = wr * 64 + mt * 16 + quad * 4 + r;
                    float v = acc[mt][nt][r] + bv_;
                    SMEM[n * 128 + (((m >> 3) ^ (n & 15)) << 3) + (m & 7)]
                        = f32_to_f16(v);
                }
            }
        }
        __syncthreads();
        // drain: per instruction a wave covers 4 full d-rows (4 x 256B)
        #pragma unroll
        for (int cc = 0; cc < 8; cc++) {
            int idx = cc * 256 + t;        // 0..2047
            int n   = idx >> 4;            // local col: h*64+d, 0..127
            int mc  = idx & 15;            // 16B chunk along s
            int d   = n & 63;
            int hh  = n >> 6;
            size_t obase = ((size_t)((bb * NH + h0 + hh) * HD + d)) * SEQ + s0;
            s8v val = *(const s8v*)&SMEM[n * 128 + ((mc ^ (n & 15)) << 3)];
            *(s8v*)(VtF + obase + mc * 8) = val;
        }
    }
}

// ---------------------------------------------------------------------------
// MFMA flash attention (R12-verified, unchanged): QBLK=128, dbuf K/V LDS,
// one barrier/iter, swapped QK^T, key-permuted staging, reg-P, raw exp2.
// ---------------------------------------------------------------------------
__global__ __launch_bounds__(256, 2)
void flash_attn(const u16* __restrict__ QF, const u16* __restrict__ KF,
                const u16* __restrict__ VtF,
                const float* __restrict__ kmax2,
                u16* __restrict__ AOF) {
    __shared__ __align__(16) u16 SM[19456];   // 2 x 9728 (dbuf)
    #define KSp(b, sub) (SM + (b) * 9728 + (sub) * 2304)
    #define VSp(b, sub) (SM + (b) * 9728 + 4608 + (sub) * 2560)

    const int t    = threadIdx.x;
    const int w    = t >> 6;
    const int lane = t & 63;
    const int quad = lane >> 4;
    const int l15  = lane & 15;

    const int bid = blockIdx.x;
    const int xcd = bid & 7;
    const int j   = bid >> 3;          // 0..63
    const int bh  = xcd * 4 + (j & 3); // 0..31
    const int q0  = (j >> 2) * 128;    // 0..15 * 128

    const size_t kvbase = (size_t)bh * SEQ * HD;
    const float km2 = kmax2[0];
    const float C1 = 0.125f * 1.44269504089f;   // scale * log2(e)

    // ---- Q fragments for g=0,1; static softmax bounds (log2 domain) ----
    h8 qf[2][2];
    float mb2[2];
    #pragma unroll
    for (int g = 0; g < 2; g++) {
        const u16* qp = QF + kvbase +
            (size_t)(q0 + g * 64 + w * 16 + l15) * HD + quad * 8;
        qf[g][0] = *(const h8*)qp;
        qf[g][1] = *(const h8*)(qp + 32);
        float qn2 = 0.f;
        #pragma unroll
        for (int st = 0; st < 2; st++)
            #pragma unroll
            for (int e = 0; e < 8; e++) {
                float v = (float)qf[g][st][e];
                qn2 += v * v;
            }
        qn2 += __shfl_xor(qn2, 16, 64);
        qn2 += __shfl_xor(qn2, 32, 64);   // row norm^2, replicated over quads
        mb2[g] = sqrtf(qn2 * km2) * C1;
    }

    f4v o[2][4];
    float lsum[2];
    #pragma unroll
    for (int g = 0; g < 2; g++) {
        #pragma unroll
        for (int nt = 0; nt < 4; nt++) o[g][nt] = (f4v){0.f, 0.f, 0.f, 0.f};
        lsum[g] = 0.f;
    }

    // ---- staging addresses; K rows permuted: phys row krow holds key pkey ----
    const int krow = t >> 3;                 // physical LDS row 0..31
    const int kdc  = (t & 7) * 8;            // 16B chunk along d
    const int pkey = (krow & 3) + 8 * ((krow >> 2) & 3) + 4 * (krow >> 4);
    const u16* kgp = KF + kvbase + (size_t)pkey * HD + kdc;
    const int vd   = t >> 2;                 // 0..63
    const int vkc  = (t & 3) * 8;            // 16B chunk along keys
    const int vcol = vkc ^ (((vd >> 3) & 3) << 3);
    const u16* vgp = VtF + (size_t)bh * HD * SEQ + (size_t)vd * SEQ + vkc;

    // prologue: tile 0 -> regs -> buf0; tile 1 -> regs; one barrier
    s8v krg0 = *(const s8v*)(kgp);
    s8v krg1 = *(const s8v*)(kgp + (size_t)32 * HD);
    s8v vrg0 = *(const s8v*)(vgp);
    s8v vrg1 = *(const s8v*)(vgp + 32);
    *(s8v*)&KSp(0, 0)[krow * 72 + kdc] = krg0;
    *(s8v*)&KSp(0, 1)[krow * 72 + kdc] = krg1;
    *(s8v*)&VSp(0, 0)[vd * 40 + vcol]  = vrg0;
    *(s8v*)&VSp(0, 1)[vd * 40 + vcol]  = vrg1;
    {
        const u16* kn = kgp + (size_t)64 * HD;
        krg0 = *(const s8v*)(kn);
        krg1 = *(const s8v*)(kn + (size_t)32 * HD);
        vrg0 = *(const s8v*)(vgp + 64);
        vrg1 = *(const s8v*)(vgp + 96);
    }
    __syncthreads();

    int cur = 0;
    for (int k0 = 0; k0 < SEQ; k0 += 64) {
        // ---- write tile t+1 (in regs) into buf^1; overlaps compute below ----
        *(s8v*)&KSp(cur ^ 1, 0)[krow * 72 + kdc] = krg0;
        *(s8v*)&KSp(cur ^ 1, 1)[krow * 72 + kdc] = krg1;
        *(s8v*)&VSp(cur ^ 1, 0)[vd * 40 + vcol]  = vrg0;
        *(s8v*)&VSp(cur ^ 1, 1)[vd * 40 + vcol]  = vrg1;
        // ---- issue loads for tile t+2 ----
        if (k0 + 128 < SEQ) {
            const u16* kn = kgp + (size_t)(k0 + 128) * HD;
            krg0 = *(const s8v*)(kn);
            krg1 = *(const s8v*)(kn + (size_t)32 * HD);
            vrg0 = *(const s8v*)(vgp + k0 + 128);
            vrg1 = *(const s8v*)(vgp + k0 + 160);
        }

        // ---- compute tile t from buf[cur] ----
        #pragma unroll
        for (int sub = 0; sub < 2; sub++) {
            const u16* kb0 = KSp(cur, sub) + l15 * 72 + quad * 8;
            const u16* kb1 = KSp(cur, sub) + (16 + l15) * 72 + quad * 8;
            h8 kh0 = *(const h8*)kb0, kh1 = *(const h8*)(kb0 + 32);
            h8 kh2 = *(const h8*)kb1, kh3 = *(const h8*)(kb1 + 32);

            // S^T per g: lane(l15,quad) reg r = S[q=l15][key 8*quad+r (+4)]
            h8 pb[2];
            #pragma unroll
            for (int g = 0; g < 2; g++) {
                f4v sc0 = (f4v){0.f, 0.f, 0.f, 0.f};
                f4v sc1 = (f4v){0.f, 0.f, 0.f, 0.f};
                __builtin_amdgcn_s_setprio(1);
                sc0 = MFMAH(kh0, qf[g][0], sc0);
                sc0 = MFMAH(kh1, qf[g][1], sc0);
                sc1 = MFMAH(kh2, qf[g][0], sc1);
                sc1 = MFMAH(kh3, qf[g][1], sc1);
                __builtin_amdgcn_s_setprio(0);

                // in-register softmax (log2 domain, raw v_exp_f32)
                float p[8];
                #pragma unroll
                for (int r = 0; r < 4; r++) {
                    p[r]     = __builtin_amdgcn_exp2f(sc0[r] * C1 - mb2[g]);
                    p[4 + r] = __builtin_amdgcn_exp2f(sc1[r] * C1 - mb2[g]);
                }
                lsum[g] += ((p[0] + p[1]) + (p[2] + p[3]))
                         + ((p[4] + p[5]) + (p[6] + p[7]));

                __half2* pp = (__half2*)&pb[g];
                pp[0] = __floats2half2_rn(p[0], p[1]);
                pp[1] = __floats2half2_rn(p[2], p[3]);
                pp[2] = __floats2half2_rn(p[4], p[5]);
                pp[3] = __floats2half2_rn(p[6], p[7]);
            }

            // O^T += V^T·P^T — each V fragment read ONCE, used for both g
            __builtin_amdgcn_s_setprio(1);
            #pragma unroll
            for (int nt = 0; nt < 4; nt++) {
                int dim = nt * 16 + l15;
                int voff = dim * 40 + ((quad * 8) ^ (((dim >> 3) & 3) << 3));
                h8 vf = *(const h8*)&VSp(cur, sub)[voff];
                o[0][nt] = MFMAH(vf, pb[0], o[0][nt]);
                o[1][nt] = MFMAH(vf, pb[1], o[1][nt]);
            }
            __builtin_amdgcn_s_setprio(0);
        }

        __syncthreads();                 // single barrier per iteration
        cur ^= 1;
    }

    // ---- epilogue: reduce l, normalize, LDS transpose (aliases SM), store ----
    float inv_l[2];
    #pragma unroll
    for (int g = 0; g < 2; g++) {
        float l = lsum[g];
        l += __shfl_xor(l, 16, 64);
        l += __shfl_xor(l, 32, 64);
        inv_l[g] = 1.0f / l;
    }

    const int b = bh >> 4;
    const int h = bh & 15;
    u16* OS = SM;                        // 128 x 64 u16 = 16 KB <= 38912 B
    #pragma unroll
    for (int g = 0; g < 2; g++) {
        const int srow = g * 64 + w * 16 + l15;   // local s 0..127
        #pragma unroll
        for (int nt = 0; nt < 4; nt++) {
            #pragma unroll
            for (int r = 0; r < 4; r++) {
                int d = nt * 16 + quad * 4 + r;
                OS[srow * 64 + (((d >> 3) ^ (srow & 7)) << 3) + (d & 7)]
                    = f32_to_f16(o[g][nt][r] * inv_l[g]);
            }
        }
    }
    __syncthreads();
    // per instruction: wave covers 8 full 128B lines of [B,S,H,D]
    #pragma unroll
    for (int cc = 0; cc < 4; cc++) {
        int idx = cc * 256 + t;          // 0..1023
        int sr  = idx >> 3;              // 0..127
        int dch = idx & 7;
        s8v val = *(const s8v*)&OS[sr * 64 + ((dch ^ (sr & 7)) << 3)];
        *(s8v*)(AOF + (((size_t)b * SEQ + q0 + sr) * NH + h) * HD + dch * 8)
            = val;
    }
    #undef KSp
    #undef VSp
}

// ---------------------------------------------------------------------------
// Out-projection fp16 MFMA GEMM — BM=128 BN=64 BK=64, grid 512 (unchanged).
// ---------------------------------------------------------------------------
__global__ __launch_bounds__(256, 2)
void gemm_out(const u16* __restrict__ AF, const u16* __restrict__ BF,
              const float* __restrict__ bias, float* __restrict__ out) {
    __shared__ __align__(16) u16 SMEM[24576];   // 48 KB

    const int t    = threadIdx.x;
    const int w    = t >> 6;
    const int lane = t & 63;
    const int quad = lane >> 4;
    const int l15  = lane & 15;
    const int wr   = w >> 1;        // m-half (64 rows)
    const int wc   = w & 1;         // n-half (32 cols)

    const int bid = blockIdx.x;
    const int xcd = bid & 7;
    const int j   = bid >> 3;              // 0..63
    const int m0  = (xcd * 4 + (j & 3)) * 128;
    const int n0  = (j >> 2) * 64;         // 0..15 * 64

    const int lr = lane >> 3;
    const int lc = (((lane & 7) ^ lr)) * 8;

    f4v acc[4][2];
    #pragma unroll
    for (int i = 0; i < 4; i++)
        #pragma unroll
        for (int jj = 0; jj < 2; jj++)
            acc[i][jj] = (f4v){0.f, 0.f, 0.f, 0.f};

#define STAGE(K0, DB) do {                                                   \
    u16* As_ = SMEM + (DB);                                                  \
    u16* Bs_ = As_ + 8192;                                                   \
    _Pragma("unroll")                                                        \
    for (int jj_ = 0; jj_ < 4; jj_++) {                                      \
        int seg = jj_ * 4 + w;                                               \
        gld16(AF + (size_t)(m0 + seg * 8 + lr) * KDIM + (K0) + lc,           \
              As_ + seg * 512);                                              \
    }                                                                        \
    _Pragma("unroll")                                                        \
    for (int jj_ = 0; jj_ < 2; jj_++) {                                      \
        int seg = jj_ * 4 + w;                                               \
        gld16(BF + (size_t)(n0 + seg * 8 + lr) * KDIM + (K0) + lc,           \
              Bs_ + seg * 512);                                              \
    }                                                                        \
} while (0)

    STAGE(0, 0);
    __syncthreads();

    int buf = 0;
    for (int k0 = 0; k0 < KDIM; k0 += 64) {
        if (k0 + 64 < KDIM) STAGE(k0 + 64, (buf ^ 1) * 12288);

        const u16* As = SMEM + buf * 12288;
        const u16* Bs = As + 8192;
        #pragma unroll
        for (int kk = 0; kk < 2; kk++) {
            const int swz = ((kk * 4 + quad) ^ (l15 & 7)) << 3;
            h8 a[4], b[2];
            #pragma unroll
            for (int mt = 0; mt < 4; mt++)
                a[mt] = *(const h8*)&As[(wr * 64 + mt * 16 + l15) * 64 + swz];
            #pragma unroll
            for (int nt = 0; nt < 2; nt++)
                b[nt] = *(const h8*)&Bs[(wc * 32 + nt * 16 + l15) * 64 + swz];
            #pragma unroll
            for (int mt = 0; mt < 4; mt++)
                #pragma unroll
                for (int nt = 0; nt < 2; nt++)
                    acc[mt][nt] = MFMAH(a[mt], b[nt], acc[mt][nt]);
        }
        __syncthreads();
        buf ^= 1;
    }
#undef STAGE

    #pragma unroll
    for (int mt = 0; mt < 4; mt++) {
        #pragma unroll
        for (int nt = 0; nt < 2; nt++) {
            int n = n0 + wc * 32 + nt * 16 + l15;
            float bv = bias[n];
            #pragma unroll
            for (int r = 0; r < 4; r++) {
                int m = m0 + wr * 64 + mt * 16 + quad * 4 + r;
                out[(size_t)m * 1024 + n] = acc[mt][nt][r] + bv;
            }
        }
    }
}

// ---------------------------------------------------------------------------
extern "C" void kernel_launch(void* const* d_in, const int* in_sizes, int n_in,
                              void* d_out, int out_size, void* d_ws, size_t ws_size,
                              hipStream_t stream) {
    const float* x  = (const float*)d_in[0];
    const float* Wq = (const float*)d_in[1];
    const float* bq = (const float*)d_in[2];
    const float* Wk = (const float*)d_in[3];
    const float* bk = (const float*)d_in[4];
    const float* Wv = (const float*)d_in[5];
    const float* bv = (const float*)d_in[6];
    const float* Wo = (const float*)d_in[7];
    const float* bo = (const float*)d_in[8];
    float* out = (float*)d_out;

    const size_t TEN = (size_t)MROWS * KDIM;     // 4,194,304
    const size_t WSZ = (size_t)KDIM * KDIM;      // 1,048,576

    u16* xF  = (u16*)d_ws;
    u16* WqF = xF + TEN;
    u16* WkF = WqF + WSZ;
    u16* WvF = WkF + WSZ;
    u16* WoF = WvF + WSZ;
    u16* QF  = WoF + WSZ;
    u16* KF  = QF + TEN;
    u16* VtF = KF + TEN;
    float* km2 = (float*)(VtF + TEN);
    float2* ropeT = (float2*)(km2 + 4);          // 2048*32 float2 = 512 KB
    u16* AOF = xF;          // x dead after qkv_gemm

    convert_f16<<<4352, 256, 0, stream>>>(x, Wq, Wk, Wv, Wo,
                                          xF, WqF, WkF, WvF, WoF, ropeT);

    hipMemsetAsync(km2, 0, 4, stream);

    qkv_gemm<<<768, 256, 0, stream>>>(xF, WqF, WkF, WvF,
                                      bq, bk, bv, ropeT, QF, KF, VtF, km2);

    flash_attn<<<512, 256, 0, stream>>>(QF, KF, VtF, km2, AOF);

    gemm_out<<<512, 256, 0, stream>>>(AOF, WoF, bo, out);
}